// Round 3
// baseline (159.682 us; speedup 1.0000x reference)
//
#include <hip/hip_runtime.h>

#define E_DIM 512
#define N_DIM 512
#define B_DIM 32
#define H_DIM 8
#define D_DIM 8
#define P3    192   // 3 * H * D

typedef _Float16 half_t;
typedef __attribute__((ext_vector_type(2))) _Float16 half2v;
typedef __attribute__((ext_vector_type(4))) _Float16 half4v;
typedef __attribute__((ext_vector_type(8))) _Float16 half8v;
typedef __attribute__((ext_vector_type(4))) float f32x4;

#define XS_STRIDE 520   // ln x-tile stride (halves)

// hopfield LDS layout (half_t units). Single manually-partitioned block so
// the intentional "read past KTb rows 9-15" stays inside the allocation.
//   KTb rows 0-8 (stride 532, rows 0-7 = K^T then V^T, row 8 = ones)
//   Kb 512x8 (packed K rows, no padding)
//   Z  512 zero halves (stride-0 A-source for g2>=2 lanes, 4-kt immediate window)
//   Xi 64x8 (+16 pad for g2=3 tail reads, value discarded)
#define SM_KT0 0
#define SM_KB0 4800
#define SM_Z0  8896
#define SM_XI0 9408
#define SM_TOT 9936
#define KT_STRIDE 532

// ---------------------------------------------------------------------------
__device__ inline float block_reduce_256(float v) {
    __shared__ float red[4];
    #pragma unroll
    for (int m = 32; m >= 1; m >>= 1) v += __shfl_xor(v, m);
    int w = threadIdx.x >> 6;
    if ((threadIdx.x & 63) == 0) red[w] = v;
    __syncthreads();
    if (threadIdx.x == 0) v = red[0] + red[1] + red[2] + red[3];
    return v;
}

__device__ inline half8v cvt8(float4 a, float4 b) {
    half8v h;
    h[0] = (half_t)a.x; h[1] = (half_t)a.y; h[2] = (half_t)a.z; h[3] = (half_t)a.w;
    h[4] = (half_t)b.x; h[5] = (half_t)b.y; h[6] = (half_t)b.z; h[7] = (half_t)b.w;
    return h;
}

__device__ inline half2v pk2(float a, float b) {
    return __builtin_bit_cast(half2v, __builtin_amdgcn_cvt_pkrtz(a, b));
}

// ---------------------------------------------------------------------------
// K0: prep. WthF = f16(W*g) in MFMA-fragment-coalesced layout.
// colsum[p'] = sum of f16-rounded w; b2[p'] = bias + W·ln_beta.
// Block 0 inits y[b]=bl, c0acc=0.
// ---------------------------------------------------------------------------
__global__ __launch_bounds__(256) void prep_w(const float* __restrict__ Wq,
                        const float* __restrict__ Wk, const float* __restrict__ Wv,
                        const float* __restrict__ gq, const float* __restrict__ gk,
                        const float* __restrict__ gv,
                        const float* __restrict__ bnq, const float* __restrict__ bnk,
                        const float* __restrict__ bnv,
                        const float* __restrict__ bq, const float* __restrict__ bk,
                        const float* __restrict__ bv,
                        const float* __restrict__ bl,
                        half_t* __restrict__ WthF, float* __restrict__ colsum,
                        float* __restrict__ b2, float* __restrict__ y,
                        float* __restrict__ c0acc) {
    int pp = blockIdx.x;     // 192
    int which = pp >> 6, p = pp & 63;
    int ct = pp >> 4, c16 = pp & 15;
    const float* W  = (which == 0) ? Wq  : (which == 1) ? Wk  : Wv;
    const float* g  = (which == 0) ? gq  : (which == 1) ? gk  : gv;
    const float* bn = (which == 0) ? bnq : (which == 1) ? bnk : bnv;
    const float* bb = (which == 0) ? bq  : (which == 1) ? bk  : bv;
    int t = threadIdx.x;
    if (pp == 0) {
        if (t < 32) y[t] = bl[0];
        if (t == 32) c0acc[0] = 0.f;
    }
    float cs = 0.f, dt = 0.f;
    #pragma unroll
    for (int l = 0; l < 2; ++l) {
        int e = t + l * 256;
        float wv = W[p * E_DIM + e];
        half_t wh = (half_t)(wv * g[e]);
        int k32 = e >> 5, g2 = (e >> 3) & 3, j = e & 7;
        WthF[(((size_t)(ct * 16 + k32) * 64) + g2 * 16 + c16) * 8 + j] = wh;
        cs += (float)wh;
        dt += wv * bn[e];
    }
    cs = block_reduce_256(cs);
    __syncthreads();
    dt = block_reduce_256(dt);
    if (t == 0) { colsum[pp] = cs; b2[pp] = dt + bb[p]; }
}

// ---------------------------------------------------------------------------
// K1: blocks 0-1023: fused LN+QKV with LDS-staged x (coalesced loads) and
// coalesced WthF B-fragments. One barrier. Blocks 1024-1055: Wl2 via MFMA.
// ---------------------------------------------------------------------------
__global__ __launch_bounds__(256) void ln_qkv_wl2(const float* __restrict__ x,
                                              const half_t* __restrict__ WthF,
                                              const float* __restrict__ b2,
                                              const float* __restrict__ colsum,
                                              half_t* __restrict__ qkv16,
                                              const float* __restrict__ Wl,
                                              const float* __restrict__ Wo,
                                              const float* __restrict__ bo,
                                              float* __restrict__ Wl2,
                                              float* __restrict__ c0acc) {
    __shared__ half_t Xs[16 * XS_STRIDE];   // 16.25 KB
    __shared__ float stats[16][2];
    if (blockIdx.x < 1024) {
        const int t = threadIdx.x;
        const int lane = t & 63;
        const int w = t >> 6;
        const int g2 = lane >> 4, c16 = lane & 15;
        const int row0 = blockIdx.x * 16;
        // ---- stage x -> f16 LDS (coalesced: 16-lane groups read 256B runs) ----
        {
            const int row = t >> 4, c = t & 15;
            const float4* xrow = (const float4*)(x + (size_t)(row0 + row) * E_DIM);
            float sx = 0.f, sxx = 0.f;
            #pragma unroll
            for (int l = 0; l < 8; ++l) {
                int f4 = c + l * 16;
                float4 a = xrow[f4];
                sx  += a.x + a.y + a.z + a.w;
                sxx += a.x*a.x + a.y*a.y + a.z*a.z + a.w*a.w;
                half4v h;
                h[0] = (half_t)a.x; h[1] = (half_t)a.y;
                h[2] = (half_t)a.z; h[3] = (half_t)a.w;
                *(half4v*)&Xs[row * XS_STRIDE + f4 * 4] = h;
            }
            #pragma unroll
            for (int m = 1; m <= 8; m <<= 1) {
                sx += __shfl_xor(sx, m); sxx += __shfl_xor(sxx, m);
            }
            if (c == 0) {
                float mean = sx * (1.f / E_DIM);
                float var  = sxx * (1.f / E_DIM) - mean * mean;
                stats[row][0] = mean;
                stats[row][1] = rsqrtf(var + 1e-5f);
            }
        }
        __syncthreads();
        // ---- K-loop: A from LDS, B from WthF (lane-contiguous) ----
        f32x4 acc[3] = {{0.f,0.f,0.f,0.f},{0.f,0.f,0.f,0.f},{0.f,0.f,0.f,0.f}};
        const half_t* wf = WthF + (size_t)w * 3 * 16 * 512;
        #pragma unroll 4
        for (int k32 = 0; k32 < 16; ++k32) {
            half8v af = *(const half8v*)&Xs[c16 * XS_STRIDE + k32 * 32 + g2 * 8];
            #pragma unroll
            for (int nt = 0; nt < 3; ++nt) {
                half8v bf = *(const half8v*)(wf + ((size_t)(nt * 16 + k32)) * 512 + lane * 8);
                acc[nt] = __builtin_amdgcn_mfma_f32_16x16x32_f16(af, bf, acc[nt], 0, 0, 0);
            }
        }
        // ---- epilogue: LN correction + scattered f16 stores ----
        #pragma unroll
        for (int nt = 0; nt < 3; ++nt) {
            int pp = w * 48 + nt * 16 + c16;
            float cs = colsum[pp], bb = b2[pp];
            int which = pp >> 6, p = pp & 63;
            int h = p >> 3, d = p & 7;
            half_t* dst0 = qkv16 + (size_t)which * (B_DIM * H_DIM * N_DIM * D_DIM);
            #pragma unroll
            for (int r = 0; r < 4; ++r) {
                int rowi = g2 * 4 + r;
                float val = stats[rowi][1] * (acc[nt][r] - stats[rowi][0] * cs) + bb;
                int ng = row0 + rowi;
                int b = ng >> 9, n = ng & 511;
                dst0[(((size_t)(b * H_DIM + h)) * N_DIM + n) * D_DIM + d] = (half_t)val;
            }
        }
    } else {
        // ---- Wl2 MFMA: blk in [0,32) ----
        const int blk = blockIdx.x - 1024;
        const int t = threadIdx.x;
        const int lane = t & 63;
        const int w = t >> 6;
        const int g2 = lane >> 4, c16 = lane & 15;
        const int n0 = blk * 16;
        const int pcol = w * 16;
        f32x4 acc = {0.f, 0.f, 0.f, 0.f};
        float pc = 0.f;
        const float* arow = Wl + (size_t)(n0 + c16) * E_DIM;
        #pragma unroll 2
        for (int k0 = 0; k0 < E_DIM; k0 += 32) {
            int kbase = k0 + g2 * 8;
            float4 a0 = *(const float4*)(arow + kbase);
            float4 a1 = *(const float4*)(arow + kbase + 4);
            if (w == 0) {
                float4 b0 = *(const float4*)(bo + kbase);
                float4 b1 = *(const float4*)(bo + kbase + 4);
                pc += a0.x*b0.x + a0.y*b0.y + a0.z*b0.z + a0.w*b0.w
                    + a1.x*b1.x + a1.y*b1.y + a1.z*b1.z + a1.w*b1.w;
            }
            half8v af = cvt8(a0, a1);
            half8v bf;
            #pragma unroll
            for (int j = 0; j < 8; ++j)
                bf[j] = (half_t)Wo[(size_t)(kbase + j) * 64 + pcol + c16];
            acc = __builtin_amdgcn_mfma_f32_16x16x32_f16(af, bf, acc, 0, 0, 0);
        }
        int p = pcol + c16, h = p >> 3, d = p & 7;
        #pragma unroll
        for (int r = 0; r < 4; ++r) {
            int n = n0 + g2 * 4 + r;
            Wl2[h * (N_DIM * D_DIM) + n * D_DIM + d] = acc[r];
        }
        if (w == 0) {
            pc += __shfl_xor(pc, 16); pc += __shfl_xor(pc, 32);
            pc += __shfl_xor(pc, 1);  pc += __shfl_xor(pc, 2);
            pc += __shfl_xor(pc, 4);  pc += __shfl_xor(pc, 8);
            if (lane == 0) atomicAdd(c0acc, pc);
        }
    }
}

// ---------------------------------------------------------------------------
// K2: MFMA Hopfield, register-resident P, occupancy-tuned.
// 8 query-segments per (b,h): grid 2048, 64 queries/block, 16 per wave.
// LDS slimmed to ~19.9 KB -> 8 blocks/CU (32 waves/CU):
//  - Kb unpadded [512][8]; S-MFMA's k>=8 zeros come from the B side
//    (bx zeroed for g2>=2), A side reads a stride-0 zero region Z for g2>=2.
//  - KTb 9 rows only; lanes c16>=9 read adjacent in-bounds LDS (zero-inited
//    gap + Kb data) -> garbage confined to unused U rows 9-15 (finite,
//    discarded).
// Chained-layout identity (round 1): 16x16x16 C/D layout == next B layout,
// so exp2(S) feeds the U-MFMA directly in registers.
// ---------------------------------------------------------------------------
__global__ __launch_bounds__(256, 8) void hopfield(const half_t* __restrict__ q16,
                                                   const half_t* __restrict__ k16,
                                                   const half_t* __restrict__ v16,
                                                   const float* __restrict__ Wl2,
                                                   const float* __restrict__ c0acc,
                                                   float* __restrict__ y) {
    __shared__ __align__(16) half_t sm[SM_TOT];   // 19872 B
    const int t = threadIdx.x;
    const int lane = t & 63;
    const int w = t >> 6;
    const int g2 = lane >> 4;
    const int c16 = lane & 15;
    const int bh = blockIdx.x >> 3, seg = blockIdx.x & 7;
    const float C = 0.25f * 1.44269504088896f;
    const half_t* kg = k16 + (size_t)bh * (N_DIM * D_DIM);
    const half_t* vg = v16 + (size_t)bh * (N_DIM * D_DIM);
    const half_t* qg = q16 + (size_t)bh * (N_DIM * D_DIM) + seg * 64 * 8;
    const float* wl2p = Wl2 + (bh & 7) * (N_DIM * D_DIM) + seg * 64 * 8;

    {   // stage K rows (packed), K^T (+ones row), zero region, Xi = C*q
        const int j0 = 2 * t;
        half8v r0 = *(const half8v*)(kg + j0 * 8);
        half8v r1 = *(const half8v*)(kg + j0 * 8 + 8);
        *(half8v*)&sm[SM_KB0 + j0 * 8]     = r0;
        *(half8v*)&sm[SM_KB0 + j0 * 8 + 8] = r1;
        #pragma unroll
        for (int d = 0; d < 8; ++d) {
            half2v p; p[0] = r0[d]; p[1] = r1[d];
            *(half2v*)&sm[SM_KT0 + d * KT_STRIDE + j0] = p;
        }
        half2v one2; one2[0] = (half_t)1.f; one2[1] = (half_t)1.f;
        *(half2v*)&sm[SM_KT0 + 8 * KT_STRIDE + j0] = one2;
        if (t < 128) {
            const half4v z4 = {};
            *(half4v*)&sm[SM_Z0 + t * 4] = z4;
        }
        if (t < 6) {   // zero the 12-half KTb->Kb gap (read by garbage lanes)
            half2v z2 = {};
            *(half2v*)&sm[9 * KT_STRIDE + t * 2] = z2;
        }
        if (t < 64) {
            half8v hq = *(const half8v*)(qg + t * 8);
            half8v h;
            #pragma unroll
            for (int d = 0; d < 8; ++d) h[d] = (half_t)(C * (float)hq[d]);
            *(half8v*)&sm[SM_XI0 + t * 8] = h;
        }
    }
    __syncthreads();

    const half_t* aTp  = sm + SM_KT0 + c16 * KT_STRIDE + g2 * 4;
    const half_t* akp0 = sm + ((g2 < 2) ? (SM_KB0 + c16 * 8 + g2 * 4) : SM_Z0);
    const int akstep4  = (g2 < 2) ? 512 : 0;   // halves per 4 kt (stride-0 lanes stay in Z)
    const f32x4 Zf = {0.f, 0.f, 0.f, 0.f};
    const half4v hz = {};
    float fsum = 0.f;

    for (int it = 0; it < 4; ++it) {
        if (it == 3) {   // swap KTb rows 0-7 to V^T (ones row untouched)
            __syncthreads();
            const int j0 = 2 * t;
            half8v r0 = *(const half8v*)(vg + j0 * 8);
            half8v r1 = *(const half8v*)(vg + j0 * 8 + 8);
            #pragma unroll
            for (int d = 0; d < 8; ++d) {
                half2v p; p[0] = r0[d]; p[1] = r1[d];
                *(half2v*)&sm[SM_KT0 + d * KT_STRIDE + j0] = p;
            }
            __syncthreads();
        }
        // B-frag (Xi^T) for this wave's q-tile; k=8..15 zeroed (B-side zeros)
        half4v bx = *(const half4v*)&sm[SM_XI0 + (w * 16 + c16) * 8 + g2 * 4];
        if (g2 >= 2) bx = hz;
        f32x4 U = Zf;
        const half_t* ap = akp0;
        #pragma unroll 2
        for (int k4 = 0; k4 < 8; ++k4) {
            #pragma unroll
            for (int u = 0; u < 4; ++u) {
                const int kt = k4 * 4 + u;
                half4v ak = *(const half4v*)(ap + u * 128);
                half4v aT = *(const half4v*)(aTp + kt * 16);
                f32x4 S = __builtin_amdgcn_mfma_f32_16x16x16f16(ak, bx, Zf, 0, 0, 0);
                half2v lo = pk2(__builtin_amdgcn_exp2f(S[0]), __builtin_amdgcn_exp2f(S[1]));
                half2v hi = pk2(__builtin_amdgcn_exp2f(S[2]), __builtin_amdgcn_exp2f(S[3]));
                half4v p = __builtin_shufflevector(lo, hi, 0, 1, 2, 3);
                U = __builtin_amdgcn_mfma_f32_16x16x16f16(aT, p, U, 0, 0, 0);
            }
            ap += akstep4;
        }
        // denominator: U row 8 (ones) lives in lane 32+c16, reg 0
        float den = __shfl(U[0], 32 + c16, 64);
        float inv = __builtin_amdgcn_rcpf(den);
        if (it < 3) {
            if (g2 < 2) {   // lanes g2<2 hold d = 4*g2 + r
                half4v h;
                #pragma unroll
                for (int r = 0; r < 4; ++r) h[r] = (half_t)(U[r] * (C * inv));
                *(half4v*)&sm[SM_XI0 + (w * 16 + c16) * 8 + g2 * 4] = h;
            }
        } else {
            if (g2 < 2) {
                float4 w0 = *(const float4*)&wl2p[(w * 16 + c16) * 8 + g2 * 4];
                fsum = inv * (U[0]*w0.x + U[1]*w0.y + U[2]*w0.z + U[3]*w0.w);
            }
        }
    }
    float tot = block_reduce_256(fsum);
    if (t == 0) atomicAdd(&y[bh >> 3], tot);
    if (blockIdx.x == 0 && t < 32) {
        atomicAdd(&y[t], c0acc[0]);
    }
}

// ---------------------------------------------------------------------------
extern "C" void kernel_launch(void* const* d_in, const int* in_sizes, int n_in,
                              void* d_out, int out_size, void* d_ws, size_t ws_size,
                              hipStream_t stream) {
    const float* x   = (const float*)d_in[0];
    const float* g_q = (const float*)d_in[1];
    const float* b_q = (const float*)d_in[2];
    const float* g_k = (const float*)d_in[3];
    const float* b_k = (const float*)d_in[4];
    const float* g_v = (const float*)d_in[5];
    const float* b_v = (const float*)d_in[6];
    const float* Wq  = (const float*)d_in[7];
    const float* bq  = (const float*)d_in[8];
    const float* Wk  = (const float*)d_in[9];
    const float* bk  = (const float*)d_in[10];
    const float* Wv  = (const float*)d_in[11];
    const float* bv  = (const float*)d_in[12];
    const float* Wo  = (const float*)d_in[13];
    const float* bo  = (const float*)d_in[14];
    const float* Wl  = (const float*)d_in[15];
    const float* bl  = (const float*)d_in[16];
    float* out = (float*)d_out;

    float* ws = (float*)d_ws;
    float*  colsum = ws;                      // 192
    float*  b2     = ws + 192;                // 192
    float*  c0acc  = ws + 384;                // 1 (+pad to 64)
    float*  Wl2    = ws + 448;                // 32768
    half_t* WthF   = (half_t*)(ws + 33216);   // 98304 halves = 49152 floats
    half_t* qkv16  = (half_t*)(ws + 82368);   // 3*1048576 halves

    half_t* q16 = qkv16;
    half_t* k16 = qkv16 + 1048576;
    half_t* v16 = qkv16 + 2097152;

    prep_w    <<<192, 256, 0, stream>>>(Wq, Wk, Wv, g_q, g_k, g_v,
                                        b_q, b_k, b_v, bq, bk, bv, bl,
                                        WthF, colsum, b2, out, c0acc);
    ln_qkv_wl2<<<1056, 256, 0, stream>>>(x, WthF, b2, colsum, qkv16,
                                         Wl, Wo, bo, Wl2, c0acc);
    hopfield  <<<2048, 256, 0, stream>>>(q16, k16, v16, Wl2, c0acc, out);
}

// Round 5
// 155.890 us; speedup vs baseline: 1.0243x; 1.0243x over previous
//
#include <hip/hip_runtime.h>

#define E_DIM 512
#define N_DIM 512
#define B_DIM 32
#define H_DIM 8
#define D_DIM 8
#define P3    192   // 3 * H * D

typedef _Float16 half_t;
typedef __attribute__((ext_vector_type(2))) _Float16 half2v;
typedef __attribute__((ext_vector_type(4))) _Float16 half4v;
typedef __attribute__((ext_vector_type(8))) _Float16 half8v;
typedef __attribute__((ext_vector_type(4))) float f32x4;
typedef __attribute__((ext_vector_type(16))) float f32x16;
typedef __attribute__((ext_vector_type(2))) unsigned int u32x2;
typedef __attribute__((ext_vector_type(4))) unsigned int u32x4;

#define XS_STRIDE 520   // ln x-tile stride (halves)
#define CQ 0.3606737602222409f   // 0.25 * log2(e)

// hopfield LDS layout (half_t units):
//   KT16: [kt(64)][row(9)][key8] kt-blocked K^T, row 8 = ones. stride 72 halves.
//   VT16: same for V^T.
//   Kb:   [512][8] packed K rows (S-MFMA A-source).
#define SM_KT0 0
#define SM_VT0 4608
#define SM_KB0 9216
#define SM_TOT 13312

// ---------------------------------------------------------------------------
__device__ inline float block_reduce_256(float v) {
    __shared__ float red[4];
    #pragma unroll
    for (int m = 32; m >= 1; m >>= 1) v += __shfl_xor(v, m);
    int w = threadIdx.x >> 6;
    if ((threadIdx.x & 63) == 0) red[w] = v;
    __syncthreads();
    if (threadIdx.x == 0) v = red[0] + red[1] + red[2] + red[3];
    return v;
}

__device__ inline half8v cvt8(float4 a, float4 b) {
    half8v h;
    h[0] = (half_t)a.x; h[1] = (half_t)a.y; h[2] = (half_t)a.z; h[3] = (half_t)a.w;
    h[4] = (half_t)b.x; h[5] = (half_t)b.y; h[6] = (half_t)b.z; h[7] = (half_t)b.w;
    return h;
}

__device__ inline unsigned pku(float a, float b) {
    return __builtin_bit_cast(unsigned, __builtin_amdgcn_cvt_pkrtz(a, b));
}

// exchange: a' = [a.lo-lanes | b.lo-lanes], b' = [a.hi-lanes | b.hi-lanes]
__device__ inline void plswap(unsigned &a, unsigned &b) {
    u32x2 r = __builtin_amdgcn_permlane32_swap(a, b, false, false);
    a = r[0]; b = r[1];
}

// broadcast lo-half lanes' value to all 64 lanes (per 32-lane column)
__device__ inline float bcast_lo(float v) {
    unsigned u = __builtin_bit_cast(unsigned, v);
    u32x2 r = __builtin_amdgcn_permlane32_swap(u, u, false, false);
    return __builtin_bit_cast(float, r[0]);
}

// ---------------------------------------------------------------------------
// K0: prep. WthF = f16(W*g) in MFMA-fragment-coalesced layout.
// colsum[p'] = sum of f16-rounded w; b2[p'] = bias + W·ln_beta.
// Block 0 inits y[b]=bl, c0acc=0.
// ---------------------------------------------------------------------------
__global__ __launch_bounds__(256) void prep_w(const float* __restrict__ Wq,
                        const float* __restrict__ Wk, const float* __restrict__ Wv,
                        const float* __restrict__ gq, const float* __restrict__ gk,
                        const float* __restrict__ gv,
                        const float* __restrict__ bnq, const float* __restrict__ bnk,
                        const float* __restrict__ bnv,
                        const float* __restrict__ bq, const float* __restrict__ bk,
                        const float* __restrict__ bv,
                        const float* __restrict__ bl,
                        half_t* __restrict__ WthF, float* __restrict__ colsum,
                        float* __restrict__ b2, float* __restrict__ y,
                        float* __restrict__ c0acc) {
    int pp = blockIdx.x;     // 192
    int which = pp >> 6, p = pp & 63;
    int ct = pp >> 4, c16 = pp & 15;
    const float* W  = (which == 0) ? Wq  : (which == 1) ? Wk  : Wv;
    const float* g  = (which == 0) ? gq  : (which == 1) ? gk  : gv;
    const float* bn = (which == 0) ? bnq : (which == 1) ? bnk : bnv;
    const float* bb = (which == 0) ? bq  : (which == 1) ? bk  : bv;
    int t = threadIdx.x;
    if (pp == 0) {
        if (t < 32) y[t] = bl[0];
        if (t == 32) c0acc[0] = 0.f;
    }
    float cs = 0.f, dt = 0.f;
    #pragma unroll
    for (int l = 0; l < 2; ++l) {
        int e = t + l * 256;
        float wv = W[p * E_DIM + e];
        half_t wh = (half_t)(wv * g[e]);
        int k32 = e >> 5, g2 = (e >> 3) & 3, j = e & 7;
        WthF[(((size_t)(ct * 16 + k32) * 64) + g2 * 16 + c16) * 8 + j] = wh;
        cs += (float)wh;
        dt += wv * bn[e];
    }
    cs = block_reduce_256(cs);
    __syncthreads();
    dt = block_reduce_256(dt);
    if (t == 0) { colsum[pp] = cs; b2[pp] = dt + bb[p]; }
}

// ---------------------------------------------------------------------------
// K1: blocks 0-1023: fused LN+QKV with LDS-staged x (coalesced loads) and
// coalesced WthF B-fragments. One barrier. Blocks 1024-1055: Wl2 via MFMA.
// q output is pre-scaled by CQ (hopfield consumes Xi = CQ * q).
// ---------------------------------------------------------------------------
__global__ __launch_bounds__(256) void ln_qkv_wl2(const float* __restrict__ x,
                                              const half_t* __restrict__ WthF,
                                              const float* __restrict__ b2,
                                              const float* __restrict__ colsum,
                                              half_t* __restrict__ qkv16,
                                              const float* __restrict__ Wl,
                                              const float* __restrict__ Wo,
                                              const float* __restrict__ bo,
                                              float* __restrict__ Wl2,
                                              float* __restrict__ c0acc) {
    __shared__ half_t Xs[16 * XS_STRIDE];   // 16.25 KB
    __shared__ float stats[16][2];
    if (blockIdx.x < 1024) {
        const int t = threadIdx.x;
        const int lane = t & 63;
        const int w = t >> 6;
        const int g2 = lane >> 4, c16 = lane & 15;
        const int row0 = blockIdx.x * 16;
        // ---- stage x -> f16 LDS (coalesced: 16-lane groups read 256B runs) ----
        {
            const int row = t >> 4, c = t & 15;
            const float4* xrow = (const float4*)(x + (size_t)(row0 + row) * E_DIM);
            float sx = 0.f, sxx = 0.f;
            #pragma unroll
            for (int l = 0; l < 8; ++l) {
                int f4 = c + l * 16;
                float4 a = xrow[f4];
                sx  += a.x + a.y + a.z + a.w;
                sxx += a.x*a.x + a.y*a.y + a.z*a.z + a.w*a.w;
                half4v h;
                h[0] = (half_t)a.x; h[1] = (half_t)a.y;
                h[2] = (half_t)a.z; h[3] = (half_t)a.w;
                *(half4v*)&Xs[row * XS_STRIDE + f4 * 4] = h;
            }
            #pragma unroll
            for (int m = 1; m <= 8; m <<= 1) {
                sx += __shfl_xor(sx, m); sxx += __shfl_xor(sxx, m);
            }
            if (c == 0) {
                float mean = sx * (1.f / E_DIM);
                float var  = sxx * (1.f / E_DIM) - mean * mean;
                stats[row][0] = mean;
                stats[row][1] = rsqrtf(var + 1e-5f);
            }
        }
        __syncthreads();
        // ---- K-loop: A from LDS, B from WthF (lane-contiguous) ----
        f32x4 acc[3] = {{0.f,0.f,0.f,0.f},{0.f,0.f,0.f,0.f},{0.f,0.f,0.f,0.f}};
        const half_t* wf = WthF + (size_t)w * 3 * 16 * 512;
        #pragma unroll 4
        for (int k32 = 0; k32 < 16; ++k32) {
            half8v af = *(const half8v*)&Xs[c16 * XS_STRIDE + k32 * 32 + g2 * 8];
            #pragma unroll
            for (int nt = 0; nt < 3; ++nt) {
                half8v bf = *(const half8v*)(wf + ((size_t)(nt * 16 + k32)) * 512 + lane * 8);
                acc[nt] = __builtin_amdgcn_mfma_f32_16x16x32_f16(af, bf, acc[nt], 0, 0, 0);
            }
        }
        // ---- epilogue: LN correction + q-prescale + scattered f16 stores ----
        #pragma unroll
        for (int nt = 0; nt < 3; ++nt) {
            int pp = w * 48 + nt * 16 + c16;
            float cs = colsum[pp], bb = b2[pp];
            float qsc = (w * 3 + nt < 4) ? CQ : 1.0f;   // which==0 third
            int which = pp >> 6, p = pp & 63;
            int h = p >> 3, d = p & 7;
            half_t* dst0 = qkv16 + (size_t)which * (B_DIM * H_DIM * N_DIM * D_DIM);
            #pragma unroll
            for (int r = 0; r < 4; ++r) {
                int rowi = g2 * 4 + r;
                float val = (stats[rowi][1] * (acc[nt][r] - stats[rowi][0] * cs) + bb) * qsc;
                int ng = row0 + rowi;
                int b = ng >> 9, n = ng & 511;
                dst0[(((size_t)(b * H_DIM + h)) * N_DIM + n) * D_DIM + d] = (half_t)val;
            }
        }
    } else {
        // ---- Wl2 MFMA: blk in [0,32) ----
        const int blk = blockIdx.x - 1024;
        const int t = threadIdx.x;
        const int lane = t & 63;
        const int w = t >> 6;
        const int g2 = lane >> 4, c16 = lane & 15;
        const int n0 = blk * 16;
        const int pcol = w * 16;
        f32x4 acc = {0.f, 0.f, 0.f, 0.f};
        float pc = 0.f;
        const float* arow = Wl + (size_t)(n0 + c16) * E_DIM;
        #pragma unroll 2
        for (int k0 = 0; k0 < E_DIM; k0 += 32) {
            int kbase = k0 + g2 * 8;
            float4 a0 = *(const float4*)(arow + kbase);
            float4 a1 = *(const float4*)(arow + kbase + 4);
            if (w == 0) {
                float4 b0 = *(const float4*)(bo + kbase);
                float4 b1 = *(const float4*)(bo + kbase + 4);
                pc += a0.x*b0.x + a0.y*b0.y + a0.z*b0.z + a0.w*b0.w
                    + a1.x*b1.x + a1.y*b1.y + a1.z*b1.z + a1.w*b1.w;
            }
            half8v af = cvt8(a0, a1);
            half8v bf;
            #pragma unroll
            for (int j = 0; j < 8; ++j)
                bf[j] = (half_t)Wo[(size_t)(kbase + j) * 64 + pcol + c16];
            acc = __builtin_amdgcn_mfma_f32_16x16x32_f16(af, bf, acc, 0, 0, 0);
        }
        int p = pcol + c16, h = p >> 3, d = p & 7;
        #pragma unroll
        for (int r = 0; r < 4; ++r) {
            int n = n0 + g2 * 4 + r;
            Wl2[h * (N_DIM * D_DIM) + n * D_DIM + d] = acc[r];
        }
        if (w == 0) {
            pc += __shfl_xor(pc, 16); pc += __shfl_xor(pc, 32);
            pc += __shfl_xor(pc, 1);  pc += __shfl_xor(pc, 2);
            pc += __shfl_xor(pc, 4);  pc += __shfl_xor(pc, 8);
            if (lane == 0) atomicAdd(c0acc, pc);
        }
    }
}

// ---------------------------------------------------------------------------
// K2: 32x32 chained-MFMA Hopfield, fully register-resident Xi.
//   S[key][q] = mfma_32x32x16(A=K rows (k=d, hi-half B zeros), B=Xi)
//   exp2 -> cvt_pkrtz -> 2x permlane32_swap per 16-key chunk aligns the
//   C/D layout (row=(r&3)+8(r>>2)+4(l>>5), col=l&31) with the next B layout
//   (k=8(l>>5)+j, col=l&31) -> U += mfma(KT_chunk, P) entirely in registers.
//   Row 8 of KT/VT = ones -> denominator; broadcast lo->hi via 1 permlane.
//   Xi update is register-only (cvt + 2 permlane), no LDS, no barriers
//   between iterations. One __syncthreads total (after staging).
// Per wave: 32 queries; block = 4 waves = 128 q; grid 1024 (4 segs x 256 bh).
// ---------------------------------------------------------------------------
__global__ __launch_bounds__(256, 4) void hopfield(const half_t* __restrict__ q16,
                                                   const half_t* __restrict__ k16,
                                                   const half_t* __restrict__ v16,
                                                   const float* __restrict__ Wl2,
                                                   const float* __restrict__ c0acc,
                                                   float* __restrict__ y) {
    __shared__ __align__(16) half_t sm[SM_TOT];   // 26624 B
    const int t = threadIdx.x;
    const int lane = t & 63;
    const int w = t >> 6;
    const int lq = lane & 31;          // query col within wave tile
    const int hi = lane >> 5;          // lane half
    const int bh = blockIdx.x >> 2, seg = blockIdx.x & 3;
    const half_t* kg = k16 + (size_t)bh * (N_DIM * D_DIM);
    const half_t* vg = v16 + (size_t)bh * (N_DIM * D_DIM);
    const half_t* qg = q16 + (size_t)bh * (N_DIM * D_DIM) + seg * 128 * 8;
    const float* wl2p = Wl2 + (bh & 7) * (N_DIM * D_DIM) + seg * 128 * 8;

    {   // stage Kb rows + kt-blocked K^T / V^T (+ ones row 8)
        const int j0 = 2 * t;
        half8v r0 = *(const half8v*)(kg + j0 * 8);
        half8v r1 = *(const half8v*)(kg + j0 * 8 + 8);
        half8v v0 = *(const half8v*)(vg + j0 * 8);
        half8v v1 = *(const half8v*)(vg + j0 * 8 + 8);
        *(half8v*)&sm[SM_KB0 + j0 * 8]     = r0;
        *(half8v*)&sm[SM_KB0 + j0 * 8 + 8] = r1;
        const int kt = t >> 2, jp = j0 & 7;
        half_t* kb = &sm[SM_KT0 + kt * 72 + jp];
        half_t* vb = &sm[SM_VT0 + kt * 72 + jp];
        #pragma unroll
        for (int d = 0; d < 8; ++d) {
            half2v pk_; pk_[0] = r0[d]; pk_[1] = r1[d];
            *(half2v*)(kb + d * 8) = pk_;
            half2v pv_; pv_[0] = v0[d]; pv_[1] = v1[d];
            *(half2v*)(vb + d * 8) = pv_;
        }
        half2v one2; one2[0] = (half_t)1.f; one2[1] = (half_t)1.f;
        *(half2v*)(kb + 64) = one2;
        *(half2v*)(vb + 64) = one2;
    }
    __syncthreads();

    // S A-source: lanes<32 walk Kb rows; lanes>=32 pinned (B-side k>=8 is zero)
    const half_t* akbase = sm + SM_KB0 + (hi ? 0 : lq * 8);
    const int akstep = hi ? 0 : 256;   // halves per 32-key tile
    // U A-source: row d' (clamped to ones row for d'>8), kt-blocked
    int rowc = lq & 15; if (rowc > 8) rowc = 8;
    const half_t* aTk = sm + SM_KT0 + hi * 72 + rowc * 8;
    const f32x16 Zf16 = {};
    float fsum = 0.f;

    // initial Xi = (CQ*q) from global (pre-scaled in ln_qkv); hi half zeroed
    half8v bx;
    {
        half8v bq = *(const half8v*)(qg + (w * 32 + lq) * 8);
        u32x4 qw = __builtin_bit_cast(u32x4, bq);
        if (hi) { qw[0] = 0u; qw[1] = 0u; qw[2] = 0u; qw[3] = 0u; }
        bx = __builtin_bit_cast(half8v, qw);
    }

    for (int it = 0; it < 4; ++it) {
        const half_t* aTit = aTk + (it == 3 ? (SM_VT0 - SM_KT0) : 0);
        const half_t* akp = akbase;
        f32x16 U = {};
        for (int tile = 0; tile < 16; ++tile) {
            half8v ak = *(const half8v*)akp;
            akp += akstep;
            half8v aT0 = *(const half8v*)(aTit + tile * 288);
            half8v aT1 = *(const half8v*)(aTit + tile * 288 + 144);
            f32x16 S = __builtin_amdgcn_mfma_f32_32x32x16_f16(ak, bx, Zf16, 0, 0, 0);
            unsigned wa = pku(__builtin_amdgcn_exp2f(S[0]),  __builtin_amdgcn_exp2f(S[1]));
            unsigned wb = pku(__builtin_amdgcn_exp2f(S[2]),  __builtin_amdgcn_exp2f(S[3]));
            unsigned wc = pku(__builtin_amdgcn_exp2f(S[4]),  __builtin_amdgcn_exp2f(S[5]));
            unsigned wd = pku(__builtin_amdgcn_exp2f(S[6]),  __builtin_amdgcn_exp2f(S[7]));
            unsigned we = pku(__builtin_amdgcn_exp2f(S[8]),  __builtin_amdgcn_exp2f(S[9]));
            unsigned wf = pku(__builtin_amdgcn_exp2f(S[10]), __builtin_amdgcn_exp2f(S[11]));
            unsigned wg = pku(__builtin_amdgcn_exp2f(S[12]), __builtin_amdgcn_exp2f(S[13]));
            unsigned wh = pku(__builtin_amdgcn_exp2f(S[14]), __builtin_amdgcn_exp2f(S[15]));
            plswap(wa, wc); plswap(wb, wd);   // keys 0-15 B-frag
            plswap(we, wg); plswap(wf, wh);   // keys 16-31 B-frag
            u32x4 c0 = {wa, wb, wc, wd};
            u32x4 c1 = {we, wf, wg, wh};
            U = __builtin_amdgcn_mfma_f32_32x32x16_f16(aT0, __builtin_bit_cast(half8v, c0), U, 0, 0, 0);
            U = __builtin_amdgcn_mfma_f32_32x32x16_f16(aT1, __builtin_bit_cast(half8v, c1), U, 0, 0, 0);
        }
        // denominator: U row 8 = lo-lane reg 4; broadcast lo->hi via permlane
        float inv = __builtin_amdgcn_rcpf(bcast_lo(U[4]));
        if (it < 3) {
            // Xi' = CQ * U/den; lanes hold d' = 4*hi + (0..3) in U[0..3]
            float ci = CQ * inv;
            unsigned W01 = pku(U[0] * ci, U[1] * ci);
            unsigned W23 = pku(U[2] * ci, U[3] * ci);
            unsigned z1 = 0u, z2 = 0u;
            plswap(W01, z1);   // W01=[lo d01|0], z1=[hi d45->lo|0]
            plswap(W23, z2);   // W23=[lo d23|0], z2=[hi d67->lo|0]
            u32x4 nb = {W01, W23, z1, z2};
            bx = __builtin_bit_cast(half8v, nb);
        } else {
            float4 wv = *(const float4*)&wl2p[(w * 32 + lq) * 8 + hi * 4];
            fsum = inv * (U[0] * wv.x + U[1] * wv.y + U[2] * wv.z + U[3] * wv.w);
        }
    }
    float tot = block_reduce_256(fsum);
    if (t == 0) atomicAdd(&y[bh >> 3], tot);
    if (blockIdx.x == 0 && t < 32) {
        atomicAdd(&y[t], c0acc[0]);
    }
}

// ---------------------------------------------------------------------------
extern "C" void kernel_launch(void* const* d_in, const int* in_sizes, int n_in,
                              void* d_out, int out_size, void* d_ws, size_t ws_size,
                              hipStream_t stream) {
    const float* x   = (const float*)d_in[0];
    const float* g_q = (const float*)d_in[1];
    const float* b_q = (const float*)d_in[2];
    const float* g_k = (const float*)d_in[3];
    const float* b_k = (const float*)d_in[4];
    const float* g_v = (const float*)d_in[5];
    const float* b_v = (const float*)d_in[6];
    const float* Wq  = (const float*)d_in[7];
    const float* bq  = (const float*)d_in[8];
    const float* Wk  = (const float*)d_in[9];
    const float* bk  = (const float*)d_in[10];
    const float* Wv  = (const float*)d_in[11];
    const float* bv  = (const float*)d_in[12];
    const float* Wo  = (const float*)d_in[13];
    const float* bo  = (const float*)d_in[14];
    const float* Wl  = (const float*)d_in[15];
    const float* bl  = (const float*)d_in[16];
    float* out = (float*)d_out;

    float* ws = (float*)d_ws;
    float*  colsum = ws;                      // 192
    float*  b2     = ws + 192;                // 192
    float*  c0acc  = ws + 384;                // 1 (+pad to 64)
    float*  Wl2    = ws + 448;                // 32768
    half_t* WthF   = (half_t*)(ws + 33216);   // 98304 halves = 49152 floats
    half_t* qkv16  = (half_t*)(ws + 82368);   // 3*1048576 halves

    half_t* q16 = qkv16;
    half_t* k16 = qkv16 + 1048576;
    half_t* v16 = qkv16 + 2097152;

    prep_w    <<<192, 256, 0, stream>>>(Wq, Wk, Wv, g_q, g_k, g_v,
                                        b_q, b_k, b_v, bq, bk, bv, bl,
                                        WthF, colsum, b2, out, c0acc);
    ln_qkv_wl2<<<1056, 256, 0, stream>>>(x, WthF, b2, colsum, qkv16,
                                         Wl, Wo, bo, Wl2, c0acc);
    hopfield  <<<1024, 256, 0, stream>>>(q16, k16, v16, Wl2, c0acc, out);
}

// Round 6
// 155.570 us; speedup vs baseline: 1.0264x; 1.0021x over previous
//
#include <hip/hip_runtime.h>

#define E_DIM 512
#define N_DIM 512
#define B_DIM 32
#define H_DIM 8
#define D_DIM 8
#define P3    192   // 3 * H * D

typedef _Float16 half_t;
typedef __attribute__((ext_vector_type(2))) _Float16 half2v;
typedef __attribute__((ext_vector_type(4))) _Float16 half4v;
typedef __attribute__((ext_vector_type(8))) _Float16 half8v;
typedef __attribute__((ext_vector_type(4))) float f32x4;
typedef __attribute__((ext_vector_type(16))) float f32x16;
typedef __attribute__((ext_vector_type(2))) unsigned int u32x2;
typedef __attribute__((ext_vector_type(4))) unsigned int u32x4;

#define XS_STRIDE 520   // ln x-tile stride (halves)
#define CQ 0.3606737602222409f   // 0.25 * log2(e)
#define LS_RS 136       // ln epilogue region stride (128 + 8 pad)

// hopfield LDS layout (half_t units):
//   KT16: [kt(64)][row(9)][key8] kt-blocked K^T, row 8 = ones. stride 72 halves.
//   VT16: same for V^T.
//   Kb:   [512][8] packed K rows (S-MFMA A-source).
#define SM_KT0 0
#define SM_VT0 4608
#define SM_KB0 9216
#define SM_TOT 13312

// ---------------------------------------------------------------------------
__device__ inline float block_reduce_256(float v) {
    __shared__ float red[4];
    #pragma unroll
    for (int m = 32; m >= 1; m >>= 1) v += __shfl_xor(v, m);
    int w = threadIdx.x >> 6;
    if ((threadIdx.x & 63) == 0) red[w] = v;
    __syncthreads();
    if (threadIdx.x == 0) v = red[0] + red[1] + red[2] + red[3];
    return v;
}

__device__ inline half8v cvt8(float4 a, float4 b) {
    half8v h;
    h[0] = (half_t)a.x; h[1] = (half_t)a.y; h[2] = (half_t)a.z; h[3] = (half_t)a.w;
    h[4] = (half_t)b.x; h[5] = (half_t)b.y; h[6] = (half_t)b.z; h[7] = (half_t)b.w;
    return h;
}

__device__ inline unsigned pku(float a, float b) {
    return __builtin_bit_cast(unsigned, __builtin_amdgcn_cvt_pkrtz(a, b));
}

// exchange: a' = [a.lo-lanes | b.lo-lanes], b' = [a.hi-lanes | b.hi-lanes]
__device__ inline void plswap(unsigned &a, unsigned &b) {
    u32x2 r = __builtin_amdgcn_permlane32_swap(a, b, false, false);
    a = r[0]; b = r[1];
}

// broadcast lo-half lanes' value to all 64 lanes (per 32-lane column)
__device__ inline float bcast_lo(float v) {
    unsigned u = __builtin_bit_cast(unsigned, v);
    u32x2 r = __builtin_amdgcn_permlane32_swap(u, u, false, false);
    return __builtin_bit_cast(float, r[0]);
}

// ---------------------------------------------------------------------------
// K0: prep. WthF = f16(W*g) in MFMA-fragment-coalesced layout.
// colsum[p'] = sum of f16-rounded w; b2[p'] = bias + W·ln_beta.
// Block 0 inits y[b]=bl, c0acc=0.
// ---------------------------------------------------------------------------
__global__ __launch_bounds__(256) void prep_w(const float* __restrict__ Wq,
                        const float* __restrict__ Wk, const float* __restrict__ Wv,
                        const float* __restrict__ gq, const float* __restrict__ gk,
                        const float* __restrict__ gv,
                        const float* __restrict__ bnq, const float* __restrict__ bnk,
                        const float* __restrict__ bnv,
                        const float* __restrict__ bq, const float* __restrict__ bk,
                        const float* __restrict__ bv,
                        const float* __restrict__ bl,
                        half_t* __restrict__ WthF, float* __restrict__ colsum,
                        float* __restrict__ b2, float* __restrict__ y,
                        float* __restrict__ c0acc) {
    int pp = blockIdx.x;     // 192
    int which = pp >> 6, p = pp & 63;
    int ct = pp >> 4, c16 = pp & 15;
    const float* W  = (which == 0) ? Wq  : (which == 1) ? Wk  : Wv;
    const float* g  = (which == 0) ? gq  : (which == 1) ? gk  : gv;
    const float* bn = (which == 0) ? bnq : (which == 1) ? bnk : bnv;
    const float* bb = (which == 0) ? bq  : (which == 1) ? bk  : bv;
    int t = threadIdx.x;
    if (pp == 0) {
        if (t < 32) y[t] = bl[0];
        if (t == 32) c0acc[0] = 0.f;
    }
    float cs = 0.f, dt = 0.f;
    #pragma unroll
    for (int l = 0; l < 2; ++l) {
        int e = t + l * 256;
        float wv = W[p * E_DIM + e];
        half_t wh = (half_t)(wv * g[e]);
        int k32 = e >> 5, g2 = (e >> 3) & 3, j = e & 7;
        WthF[(((size_t)(ct * 16 + k32) * 64) + g2 * 16 + c16) * 8 + j] = wh;
        cs += (float)wh;
        dt += wv * bn[e];
    }
    cs = block_reduce_256(cs);
    __syncthreads();
    dt = block_reduce_256(dt);
    if (t == 0) { colsum[pp] = cs; b2[pp] = dt + bb[p]; }
}

// ---------------------------------------------------------------------------
// K1: blocks 0-1023: fused LN+QKV with LDS-staged x (coalesced loads) and
// coalesced WthF B-fragments. Epilogue transposes through LDS so the qkv16
// stores are fully coalesced 8B runs. Blocks 1024-1055: Wl2 via MFMA.
// q output is pre-scaled by CQ (hopfield consumes Xi = CQ * q).
// ---------------------------------------------------------------------------
__global__ __launch_bounds__(256) void ln_qkv_wl2(const float* __restrict__ x,
                                              const half_t* __restrict__ WthF,
                                              const float* __restrict__ b2,
                                              const float* __restrict__ colsum,
                                              half_t* __restrict__ qkv16,
                                              const float* __restrict__ Wl,
                                              const float* __restrict__ Wo,
                                              const float* __restrict__ bo,
                                              float* __restrict__ Wl2,
                                              float* __restrict__ c0acc) {
    __shared__ half_t Xs[16 * XS_STRIDE];   // 16.25 KB
    __shared__ half_t Ls[24 * LS_RS];       // 6.4 KB epilogue transpose
    __shared__ float stats[16][2];
    if (blockIdx.x < 1024) {
        const int t = threadIdx.x;
        const int lane = t & 63;
        const int w = t >> 6;
        const int g2 = lane >> 4, c16 = lane & 15;
        const int row0 = blockIdx.x * 16;
        // ---- stage x -> f16 LDS (coalesced: 16-lane groups read 256B runs) ----
        {
            const int row = t >> 4, c = t & 15;
            const float4* xrow = (const float4*)(x + (size_t)(row0 + row) * E_DIM);
            float sx = 0.f, sxx = 0.f;
            #pragma unroll
            for (int l = 0; l < 8; ++l) {
                int f4 = c + l * 16;
                float4 a = xrow[f4];
                sx  += a.x + a.y + a.z + a.w;
                sxx += a.x*a.x + a.y*a.y + a.z*a.z + a.w*a.w;
                half4v h;
                h[0] = (half_t)a.x; h[1] = (half_t)a.y;
                h[2] = (half_t)a.z; h[3] = (half_t)a.w;
                *(half4v*)&Xs[row * XS_STRIDE + f4 * 4] = h;
            }
            #pragma unroll
            for (int m = 1; m <= 8; m <<= 1) {
                sx += __shfl_xor(sx, m); sxx += __shfl_xor(sxx, m);
            }
            if (c == 0) {
                float mean = sx * (1.f / E_DIM);
                float var  = sxx * (1.f / E_DIM) - mean * mean;
                stats[row][0] = mean;
                stats[row][1] = rsqrtf(var + 1e-5f);
            }
        }
        __syncthreads();
        // ---- K-loop: A from LDS, B from WthF (lane-contiguous) ----
        f32x4 acc[3] = {{0.f,0.f,0.f,0.f},{0.f,0.f,0.f,0.f},{0.f,0.f,0.f,0.f}};
        const half_t* wf = WthF + (size_t)w * 3 * 16 * 512;
        #pragma unroll 4
        for (int k32 = 0; k32 < 16; ++k32) {
            half8v af = *(const half8v*)&Xs[c16 * XS_STRIDE + k32 * 32 + g2 * 8];
            #pragma unroll
            for (int nt = 0; nt < 3; ++nt) {
                half8v bf = *(const half8v*)(wf + ((size_t)(nt * 16 + k32)) * 512 + lane * 8);
                acc[nt] = __builtin_amdgcn_mfma_f32_16x16x32_f16(af, bf, acc[nt], 0, 0, 0);
            }
        }
        // ---- epilogue: LN correction + q-prescale -> LDS transpose ----
        #pragma unroll
        for (int nt = 0; nt < 3; ++nt) {
            int pp = w * 48 + nt * 16 + c16;
            float cs = colsum[pp], bb = b2[pp];
            float qsc = (pp < 64) ? CQ : 1.0f;
            int region = pp >> 3, d = pp & 7;
            #pragma unroll
            for (int r = 0; r < 4; ++r) {
                int rowi = g2 * 4 + r;
                float val = (stats[rowi][1] * (acc[nt][r] - stats[rowi][0] * cs) + bb) * qsc;
                Ls[region * LS_RS + rowi * 8 + d] = (half_t)val;
            }
        }
        __syncthreads();
        // ---- coalesced stores: 768 chunks of 8B, 3 per thread ----
        const int b = row0 >> 9, n0 = row0 & 511;
        #pragma unroll
        for (int l = 0; l < 3; ++l) {
            int c = t + l * 256;
            int region = c >> 5, off = (c & 31) * 4;   // off = rowi*8 + d0
            int which = region >> 3, h = region & 7;
            half4v v = *(const half4v*)&Ls[region * LS_RS + off];
            half_t* dst0 = qkv16 + (size_t)which * (B_DIM * H_DIM * N_DIM * D_DIM);
            int rowi = off >> 3, d0 = off & 7;
            *(half4v*)&dst0[(((size_t)(b * H_DIM + h)) * N_DIM + n0 + rowi) * D_DIM + d0] = v;
        }
    } else {
        // ---- Wl2 MFMA: blk in [0,32) ----
        const int blk = blockIdx.x - 1024;
        const int t = threadIdx.x;
        const int lane = t & 63;
        const int w = t >> 6;
        const int g2 = lane >> 4, c16 = lane & 15;
        const int n0 = blk * 16;
        const int pcol = w * 16;
        f32x4 acc = {0.f, 0.f, 0.f, 0.f};
        float pc = 0.f;
        const float* arow = Wl + (size_t)(n0 + c16) * E_DIM;
        #pragma unroll 2
        for (int k0 = 0; k0 < E_DIM; k0 += 32) {
            int kbase = k0 + g2 * 8;
            float4 a0 = *(const float4*)(arow + kbase);
            float4 a1 = *(const float4*)(arow + kbase + 4);
            if (w == 0) {
                float4 b0 = *(const float4*)(bo + kbase);
                float4 b1 = *(const float4*)(bo + kbase + 4);
                pc += a0.x*b0.x + a0.y*b0.y + a0.z*b0.z + a0.w*b0.w
                    + a1.x*b1.x + a1.y*b1.y + a1.z*b1.z + a1.w*b1.w;
            }
            half8v af = cvt8(a0, a1);
            half8v bf;
            #pragma unroll
            for (int j = 0; j < 8; ++j)
                bf[j] = (half_t)Wo[(size_t)(kbase + j) * 64 + pcol + c16];
            acc = __builtin_amdgcn_mfma_f32_16x16x32_f16(af, bf, acc, 0, 0, 0);
        }
        int p = pcol + c16, h = p >> 3, d = p & 7;
        #pragma unroll
        for (int r = 0; r < 4; ++r) {
            int n = n0 + g2 * 4 + r;
            Wl2[h * (N_DIM * D_DIM) + n * D_DIM + d] = acc[r];
        }
        if (w == 0) {
            pc += __shfl_xor(pc, 16); pc += __shfl_xor(pc, 32);
            pc += __shfl_xor(pc, 1);  pc += __shfl_xor(pc, 2);
            pc += __shfl_xor(pc, 4);  pc += __shfl_xor(pc, 8);
            if (lane == 0) atomicAdd(c0acc, pc);
        }
    }
}

// ---------------------------------------------------------------------------
// K2: 32x32 chained-MFMA Hopfield, register-resident Xi, software-pipelined.
// 2-stage pipeline: tile t+1's ds_read + S-MFMA issue before tile t's
// exp/pack/U chain -> each wave carries 2 independent chains (the round-5
// version was latency-bound: one serial chain x 4 waves/SIMD).
// All lanes walk Kb rows (hi lanes duplicate lo addresses -> LDS broadcast;
// their A-values are multiplied by the zeroed hi half of B). s_setprio(1)
// around the compute cluster (independent waves, attn-like evidence).
// ---------------------------------------------------------------------------
__global__ __launch_bounds__(256, 4) void hopfield(const half_t* __restrict__ q16,
                                                   const half_t* __restrict__ k16,
                                                   const half_t* __restrict__ v16,
                                                   const float* __restrict__ Wl2,
                                                   const float* __restrict__ c0acc,
                                                   float* __restrict__ y) {
    __shared__ __align__(16) half_t sm[SM_TOT];   // 26624 B
    const int t = threadIdx.x;
    const int lane = t & 63;
    const int w = t >> 6;
    const int lq = lane & 31;          // query col within wave tile
    const int hi = lane >> 5;          // lane half
    const int bh = blockIdx.x >> 2, seg = blockIdx.x & 3;
    const half_t* kg = k16 + (size_t)bh * (N_DIM * D_DIM);
    const half_t* vg = v16 + (size_t)bh * (N_DIM * D_DIM);
    const half_t* qg = q16 + (size_t)bh * (N_DIM * D_DIM) + seg * 128 * 8;
    const float* wl2p = Wl2 + (bh & 7) * (N_DIM * D_DIM) + seg * 128 * 8;

    {   // stage Kb rows + kt-blocked K^T / V^T (+ ones row 8)
        const int j0 = 2 * t;
        half8v r0 = *(const half8v*)(kg + j0 * 8);
        half8v r1 = *(const half8v*)(kg + j0 * 8 + 8);
        half8v v0 = *(const half8v*)(vg + j0 * 8);
        half8v v1 = *(const half8v*)(vg + j0 * 8 + 8);
        *(half8v*)&sm[SM_KB0 + j0 * 8]     = r0;
        *(half8v*)&sm[SM_KB0 + j0 * 8 + 8] = r1;
        const int kt = t >> 2, jp = j0 & 7;
        half_t* kb = &sm[SM_KT0 + kt * 72 + jp];
        half_t* vb = &sm[SM_VT0 + kt * 72 + jp];
        #pragma unroll
        for (int d = 0; d < 8; ++d) {
            half2v pk_; pk_[0] = r0[d]; pk_[1] = r1[d];
            *(half2v*)(kb + d * 8) = pk_;
            half2v pv_; pv_[0] = v0[d]; pv_[1] = v1[d];
            *(half2v*)(vb + d * 8) = pv_;
        }
        half2v one2; one2[0] = (half_t)1.f; one2[1] = (half_t)1.f;
        *(half2v*)(kb + 64) = one2;
        *(half2v*)(vb + 64) = one2;
    }
    __syncthreads();

    // S A-source: all lanes walk Kb row lq (hi lanes: same addr as lo sibling)
    const half_t* akb = sm + SM_KB0 + lq * 8;
    // U A-source: row d' (clamped to ones row for d'>8), kt-blocked
    int rowc = lq & 15; if (rowc > 8) rowc = 8;
    const half_t* aTk = sm + SM_KT0 + hi * 72 + rowc * 8;
    const half_t* aVk = sm + SM_VT0 + hi * 72 + rowc * 8;
    const f32x16 Zf16 = {};
    float fsum = 0.f;

    // initial Xi = (CQ*q) from global (pre-scaled in ln_qkv); hi half zeroed
    half8v bx;
    {
        half8v bq = *(const half8v*)(qg + (w * 32 + lq) * 8);
        u32x4 qw = __builtin_bit_cast(u32x4, bq);
        if (hi) { qw[0] = 0u; qw[1] = 0u; qw[2] = 0u; qw[3] = 0u; }
        bx = __builtin_bit_cast(half8v, qw);
    }

    for (int it = 0; it < 4; ++it) {
        const half_t* aTit = (it == 3) ? aVk : aTk;
        f32x16 U = {};
        half8v ak0 = *(const half8v*)akb;
        f32x16 Sn = __builtin_amdgcn_mfma_f32_32x32x16_f16(ak0, bx, Zf16, 0, 0, 0);
        #pragma unroll 4
        for (int tile = 0; tile < 16; ++tile) {
            f32x16 S = Sn;
            if (tile < 15) {
                half8v akn = *(const half8v*)(akb + (tile + 1) * 256);
                Sn = __builtin_amdgcn_mfma_f32_32x32x16_f16(akn, bx, Zf16, 0, 0, 0);
            }
            half8v aT0 = *(const half8v*)(aTit + tile * 288);
            half8v aT1 = *(const half8v*)(aTit + tile * 288 + 144);
            __builtin_amdgcn_s_setprio(1);
            unsigned wa = pku(__builtin_amdgcn_exp2f(S[0]),  __builtin_amdgcn_exp2f(S[1]));
            unsigned wb = pku(__builtin_amdgcn_exp2f(S[2]),  __builtin_amdgcn_exp2f(S[3]));
            unsigned wc = pku(__builtin_amdgcn_exp2f(S[4]),  __builtin_amdgcn_exp2f(S[5]));
            unsigned wd = pku(__builtin_amdgcn_exp2f(S[6]),  __builtin_amdgcn_exp2f(S[7]));
            unsigned we = pku(__builtin_amdgcn_exp2f(S[8]),  __builtin_amdgcn_exp2f(S[9]));
            unsigned wf = pku(__builtin_amdgcn_exp2f(S[10]), __builtin_amdgcn_exp2f(S[11]));
            unsigned wg = pku(__builtin_amdgcn_exp2f(S[12]), __builtin_amdgcn_exp2f(S[13]));
            unsigned wh = pku(__builtin_amdgcn_exp2f(S[14]), __builtin_amdgcn_exp2f(S[15]));
            plswap(wa, wc); plswap(wb, wd);   // keys 0-15 B-frag
            plswap(we, wg); plswap(wf, wh);   // keys 16-31 B-frag
            u32x4 c0 = {wa, wb, wc, wd};
            u32x4 c1 = {we, wf, wg, wh};
            U = __builtin_amdgcn_mfma_f32_32x32x16_f16(aT0, __builtin_bit_cast(half8v, c0), U, 0, 0, 0);
            U = __builtin_amdgcn_mfma_f32_32x32x16_f16(aT1, __builtin_bit_cast(half8v, c1), U, 0, 0, 0);
            __builtin_amdgcn_s_setprio(0);
        }
        // denominator: U row 8 = lo-lane reg 4; broadcast lo->hi via permlane
        float inv = __builtin_amdgcn_rcpf(bcast_lo(U[4]));
        if (it < 3) {
            // Xi' = CQ * U/den; lanes hold d' = 4*hi + (0..3) in U[0..3]
            float ci = CQ * inv;
            unsigned W01 = pku(U[0] * ci, U[1] * ci);
            unsigned W23 = pku(U[2] * ci, U[3] * ci);
            unsigned z1 = 0u, z2 = 0u;
            plswap(W01, z1);   // W01=[lo d01|0], z1=[hi d45->lo|0]
            plswap(W23, z2);   // W23=[lo d23|0], z2=[hi d67->lo|0]
            u32x4 nb = {W01, W23, z1, z2};
            bx = __builtin_bit_cast(half8v, nb);
        } else {
            float4 wv = *(const float4*)&wl2p[(w * 32 + lq) * 8 + hi * 4];
            fsum = inv * (U[0] * wv.x + U[1] * wv.y + U[2] * wv.z + U[3] * wv.w);
        }
    }
    float tot = block_reduce_256(fsum);
    if (t == 0) atomicAdd(&y[bh >> 3], tot);
    if (blockIdx.x == 0 && t < 32) {
        atomicAdd(&y[t], c0acc[0]);
    }
}

// ---------------------------------------------------------------------------
extern "C" void kernel_launch(void* const* d_in, const int* in_sizes, int n_in,
                              void* d_out, int out_size, void* d_ws, size_t ws_size,
                              hipStream_t stream) {
    const float* x   = (const float*)d_in[0];
    const float* g_q = (const float*)d_in[1];
    const float* b_q = (const float*)d_in[2];
    const float* g_k = (const float*)d_in[3];
    const float* b_k = (const float*)d_in[4];
    const float* g_v = (const float*)d_in[5];
    const float* b_v = (const float*)d_in[6];
    const float* Wq  = (const float*)d_in[7];
    const float* bq  = (const float*)d_in[8];
    const float* Wk  = (const float*)d_in[9];
    const float* bk  = (const float*)d_in[10];
    const float* Wv  = (const float*)d_in[11];
    const float* bv  = (const float*)d_in[12];
    const float* Wo  = (const float*)d_in[13];
    const float* bo  = (const float*)d_in[14];
    const float* Wl  = (const float*)d_in[15];
    const float* bl  = (const float*)d_in[16];
    float* out = (float*)d_out;

    float* ws = (float*)d_ws;
    float*  colsum = ws;                      // 192
    float*  b2     = ws + 192;                // 192
    float*  c0acc  = ws + 384;                // 1 (+pad to 64)
    float*  Wl2    = ws + 448;                // 32768
    half_t* WthF   = (half_t*)(ws + 33216);   // 98304 halves = 49152 floats
    half_t* qkv16  = (half_t*)(ws + 82368);   // 3*1048576 halves

    half_t* q16 = qkv16;
    half_t* k16 = qkv16 + 1048576;
    half_t* v16 = qkv16 + 2097152;

    prep_w    <<<192, 256, 0, stream>>>(Wq, Wk, Wv, g_q, g_k, g_v,
                                        b_q, b_k, b_v, bq, bk, bv, bl,
                                        WthF, colsum, b2, out, c0acc);
    ln_qkv_wl2<<<1056, 256, 0, stream>>>(x, WthF, b2, colsum, qkv16,
                                         Wl, Wo, bo, Wl2, c0acc);
    hopfield  <<<1024, 256, 0, stream>>>(q16, k16, v16, Wl2, c0acc, out);
}

// Round 7
// 152.134 us; speedup vs baseline: 1.0496x; 1.0226x over previous
//
#include <hip/hip_runtime.h>

#define E_DIM 512
#define N_DIM 512
#define B_DIM 32
#define H_DIM 8
#define D_DIM 8
#define P3    192   // 3 * H * D

typedef _Float16 half_t;
typedef __attribute__((ext_vector_type(2))) _Float16 half2v;
typedef __attribute__((ext_vector_type(4))) _Float16 half4v;
typedef __attribute__((ext_vector_type(8))) _Float16 half8v;
typedef __attribute__((ext_vector_type(4))) float f32x4;
typedef __attribute__((ext_vector_type(16))) float f32x16;
typedef __attribute__((ext_vector_type(2))) unsigned int u32x2;
typedef __attribute__((ext_vector_type(4))) unsigned int u32x4;

#define XS_STRIDE 520   // ln x-tile stride (halves)
#define CQ 0.3606737602222409f   // 0.25 * log2(e)
#define LS_RS 136       // ln epilogue region stride (128 + 8 pad)

// hopfield LDS layout (half_t units):
//   KT16: [kt(64)][row(9)][key8] kt-blocked K^T, row 8 = ones. stride 72 halves.
//   VT16: same for V^T.
//   Kb:   [512][8] packed K rows (S-MFMA A-source).
#define SM_KT0 0
#define SM_VT0 4608
#define SM_KB0 9216
#define SM_TOT 13312

// ---------------------------------------------------------------------------
__device__ inline float block_reduce_256(float v) {
    __shared__ float red[4];
    #pragma unroll
    for (int m = 32; m >= 1; m >>= 1) v += __shfl_xor(v, m);
    int w = threadIdx.x >> 6;
    if ((threadIdx.x & 63) == 0) red[w] = v;
    __syncthreads();
    if (threadIdx.x == 0) v = red[0] + red[1] + red[2] + red[3];
    return v;
}

__device__ inline half8v cvt8(float4 a, float4 b) {
    half8v h;
    h[0] = (half_t)a.x; h[1] = (half_t)a.y; h[2] = (half_t)a.z; h[3] = (half_t)a.w;
    h[4] = (half_t)b.x; h[5] = (half_t)b.y; h[6] = (half_t)b.z; h[7] = (half_t)b.w;
    return h;
}

__device__ inline unsigned pku(float a, float b) {
    return __builtin_bit_cast(unsigned, __builtin_amdgcn_cvt_pkrtz(a, b));
}

// exchange: a' = [a.lo-lanes | b.lo-lanes], b' = [a.hi-lanes | b.hi-lanes]
__device__ inline void plswap(unsigned &a, unsigned &b) {
    u32x2 r = __builtin_amdgcn_permlane32_swap(a, b, false, false);
    a = r[0]; b = r[1];
}

// broadcast lo-half lanes' value to all 64 lanes (per 32-lane column)
__device__ inline float bcast_lo(float v) {
    unsigned u = __builtin_bit_cast(unsigned, v);
    u32x2 r = __builtin_amdgcn_permlane32_swap(u, u, false, false);
    return __builtin_bit_cast(float, r[0]);
}

// ---------------------------------------------------------------------------
// K0: prep. WthF = f16(W*g) in MFMA-fragment-coalesced layout.
// colsum[p'] = sum of f16-rounded w; b2[p'] = bias + W·ln_beta.
// Block 0 inits y[b]=bl, c0acc=0.
// ---------------------------------------------------------------------------
__global__ __launch_bounds__(256) void prep_w(const float* __restrict__ Wq,
                        const float* __restrict__ Wk, const float* __restrict__ Wv,
                        const float* __restrict__ gq, const float* __restrict__ gk,
                        const float* __restrict__ gv,
                        const float* __restrict__ bnq, const float* __restrict__ bnk,
                        const float* __restrict__ bnv,
                        const float* __restrict__ bq, const float* __restrict__ bk,
                        const float* __restrict__ bv,
                        const float* __restrict__ bl,
                        half_t* __restrict__ WthF, float* __restrict__ colsum,
                        float* __restrict__ b2, float* __restrict__ y,
                        float* __restrict__ c0acc) {
    int pp = blockIdx.x;     // 192
    int which = pp >> 6, p = pp & 63;
    int ct = pp >> 4, c16 = pp & 15;
    const float* W  = (which == 0) ? Wq  : (which == 1) ? Wk  : Wv;
    const float* g  = (which == 0) ? gq  : (which == 1) ? gk  : gv;
    const float* bn = (which == 0) ? bnq : (which == 1) ? bnk : bnv;
    const float* bb = (which == 0) ? bq  : (which == 1) ? bk  : bv;
    int t = threadIdx.x;
    if (pp == 0) {
        if (t < 32) y[t] = bl[0];
        if (t == 32) c0acc[0] = 0.f;
    }
    float cs = 0.f, dt = 0.f;
    #pragma unroll
    for (int l = 0; l < 2; ++l) {
        int e = t + l * 256;
        float wv = W[p * E_DIM + e];
        half_t wh = (half_t)(wv * g[e]);
        int k32 = e >> 5, g2 = (e >> 3) & 3, j = e & 7;
        WthF[(((size_t)(ct * 16 + k32) * 64) + g2 * 16 + c16) * 8 + j] = wh;
        cs += (float)wh;
        dt += wv * bn[e];
    }
    cs = block_reduce_256(cs);
    __syncthreads();
    dt = block_reduce_256(dt);
    if (t == 0) { colsum[pp] = cs; b2[pp] = dt + bb[p]; }
}

// ---------------------------------------------------------------------------
// K1: blocks 0-1023: fused LN+QKV with LDS-staged x (coalesced loads) and
// coalesced WthF B-fragments. k32=0 B-frags prefetched pre-barrier so the
// K-loop entry doesn't eat a cold L2 latency. Epilogue transposes through
// LDS -> coalesced 8B stores. Blocks 1024-1055: Wl2 via MFMA.
// q output is pre-scaled by CQ (hopfield consumes Xi = CQ * q).
// ---------------------------------------------------------------------------
__global__ __launch_bounds__(256) void ln_qkv_wl2(const float* __restrict__ x,
                                              const half_t* __restrict__ WthF,
                                              const float* __restrict__ b2,
                                              const float* __restrict__ colsum,
                                              half_t* __restrict__ qkv16,
                                              const float* __restrict__ Wl,
                                              const float* __restrict__ Wo,
                                              const float* __restrict__ bo,
                                              float* __restrict__ Wl2,
                                              float* __restrict__ c0acc) {
    __shared__ half_t Xs[16 * XS_STRIDE];   // 16.25 KB
    __shared__ half_t Ls[24 * LS_RS];       // 6.4 KB epilogue transpose
    __shared__ float stats[16][2];
    if (blockIdx.x < 1024) {
        const int t = threadIdx.x;
        const int lane = t & 63;
        const int w = t >> 6;
        const int g2 = lane >> 4, c16 = lane & 15;
        const int row0 = blockIdx.x * 16;
        const half_t* wf = WthF + (size_t)w * 3 * 16 * 512;
        // ---- prefetch k32=0 B-frags (L2) to overlap with x HBM latency ----
        half8v pb0 = *(const half8v*)(wf + (size_t)( 0) * 512 + lane * 8);
        half8v pb1 = *(const half8v*)(wf + (size_t)(16) * 512 + lane * 8);
        half8v pb2 = *(const half8v*)(wf + (size_t)(32) * 512 + lane * 8);
        // ---- stage x -> f16 LDS (coalesced: 16-lane groups read 256B runs) ----
        {
            const int row = t >> 4, c = t & 15;
            const float4* xrow = (const float4*)(x + (size_t)(row0 + row) * E_DIM);
            float sx = 0.f, sxx = 0.f;
            #pragma unroll
            for (int l = 0; l < 8; ++l) {
                int f4 = c + l * 16;
                float4 a = xrow[f4];
                sx  += a.x + a.y + a.z + a.w;
                sxx += a.x*a.x + a.y*a.y + a.z*a.z + a.w*a.w;
                half4v h;
                h[0] = (half_t)a.x; h[1] = (half_t)a.y;
                h[2] = (half_t)a.z; h[3] = (half_t)a.w;
                *(half4v*)&Xs[row * XS_STRIDE + f4 * 4] = h;
            }
            #pragma unroll
            for (int m = 1; m <= 8; m <<= 1) {
                sx += __shfl_xor(sx, m); sxx += __shfl_xor(sxx, m);
            }
            if (c == 0) {
                float mean = sx * (1.f / E_DIM);
                float var  = sxx * (1.f / E_DIM) - mean * mean;
                stats[row][0] = mean;
                stats[row][1] = rsqrtf(var + 1e-5f);
            }
        }
        __syncthreads();
        // ---- K-loop: A from LDS, B from WthF (k32=0 from prefetch regs) ----
        f32x4 acc[3] = {{0.f,0.f,0.f,0.f},{0.f,0.f,0.f,0.f},{0.f,0.f,0.f,0.f}};
        {
            half8v af = *(const half8v*)&Xs[c16 * XS_STRIDE + g2 * 8];
            acc[0] = __builtin_amdgcn_mfma_f32_16x16x32_f16(af, pb0, acc[0], 0, 0, 0);
            acc[1] = __builtin_amdgcn_mfma_f32_16x16x32_f16(af, pb1, acc[1], 0, 0, 0);
            acc[2] = __builtin_amdgcn_mfma_f32_16x16x32_f16(af, pb2, acc[2], 0, 0, 0);
        }
        #pragma unroll 5
        for (int k32 = 1; k32 < 16; ++k32) {
            half8v af = *(const half8v*)&Xs[c16 * XS_STRIDE + k32 * 32 + g2 * 8];
            #pragma unroll
            for (int nt = 0; nt < 3; ++nt) {
                half8v bf = *(const half8v*)(wf + ((size_t)(nt * 16 + k32)) * 512 + lane * 8);
                acc[nt] = __builtin_amdgcn_mfma_f32_16x16x32_f16(af, bf, acc[nt], 0, 0, 0);
            }
        }
        // ---- epilogue: LN correction + q-prescale -> LDS transpose ----
        #pragma unroll
        for (int nt = 0; nt < 3; ++nt) {
            int pp = w * 48 + nt * 16 + c16;
            float cs = colsum[pp], bb = b2[pp];
            float qsc = (pp < 64) ? CQ : 1.0f;
            int region = pp >> 3, d = pp & 7;
            #pragma unroll
            for (int r = 0; r < 4; ++r) {
                int rowi = g2 * 4 + r;
                float val = (stats[rowi][1] * (acc[nt][r] - stats[rowi][0] * cs) + bb) * qsc;
                Ls[region * LS_RS + rowi * 8 + d] = (half_t)val;
            }
        }
        __syncthreads();
        // ---- coalesced stores: 768 chunks of 8B, 3 per thread ----
        const int b = row0 >> 9, n0 = row0 & 511;
        #pragma unroll
        for (int l = 0; l < 3; ++l) {
            int c = t + l * 256;
            int region = c >> 5, off = (c & 31) * 4;   // off = rowi*8 + d0
            int which = region >> 3, h = region & 7;
            half4v v = *(const half4v*)&Ls[region * LS_RS + off];
            half_t* dst0 = qkv16 + (size_t)which * (B_DIM * H_DIM * N_DIM * D_DIM);
            int rowi = off >> 3, d0 = off & 7;
            *(half4v*)&dst0[(((size_t)(b * H_DIM + h)) * N_DIM + n0 + rowi) * D_DIM + d0] = v;
        }
    } else {
        // ---- Wl2 MFMA: blk in [0,32) ----
        const int blk = blockIdx.x - 1024;
        const int t = threadIdx.x;
        const int lane = t & 63;
        const int w = t >> 6;
        const int g2 = lane >> 4, c16 = lane & 15;
        const int n0 = blk * 16;
        const int pcol = w * 16;
        f32x4 acc = {0.f, 0.f, 0.f, 0.f};
        float pc = 0.f;
        const float* arow = Wl + (size_t)(n0 + c16) * E_DIM;
        #pragma unroll 2
        for (int k0 = 0; k0 < E_DIM; k0 += 32) {
            int kbase = k0 + g2 * 8;
            float4 a0 = *(const float4*)(arow + kbase);
            float4 a1 = *(const float4*)(arow + kbase + 4);
            if (w == 0) {
                float4 b0 = *(const float4*)(bo + kbase);
                float4 b1 = *(const float4*)(bo + kbase + 4);
                pc += a0.x*b0.x + a0.y*b0.y + a0.z*b0.z + a0.w*b0.w
                    + a1.x*b1.x + a1.y*b1.y + a1.z*b1.z + a1.w*b1.w;
            }
            half8v af = cvt8(a0, a1);
            half8v bf;
            #pragma unroll
            for (int j = 0; j < 8; ++j)
                bf[j] = (half_t)Wo[(size_t)(kbase + j) * 64 + pcol + c16];
            acc = __builtin_amdgcn_mfma_f32_16x16x32_f16(af, bf, acc, 0, 0, 0);
        }
        int p = pcol + c16, h = p >> 3, d = p & 7;
        #pragma unroll
        for (int r = 0; r < 4; ++r) {
            int n = n0 + g2 * 4 + r;
            Wl2[h * (N_DIM * D_DIM) + n * D_DIM + d] = acc[r];
        }
        if (w == 0) {
            pc += __shfl_xor(pc, 16); pc += __shfl_xor(pc, 32);
            pc += __shfl_xor(pc, 1);  pc += __shfl_xor(pc, 2);
            pc += __shfl_xor(pc, 4);  pc += __shfl_xor(pc, 8);
            if (lane == 0) atomicAdd(c0acc, pc);
        }
    }
}

// ---------------------------------------------------------------------------
// K2: 32x32 chained-MFMA Hopfield, TWO chains per wave.
// Each wave owns 64 queries = two independent S->exp->U chains (A: q=lq,
// B: q=32+lq) that SHARE the ak/aT LDS fragments: halves LDS instructions
// per query and gives true 2-way ILP to hide the S->exp->U serial latency
// (R6's software pipeline only overlapped the cheap S-MFMA; this overlaps
// the whole chain). Grid 512 (2 blocks/CU, 8 waves/CU) — ILP replaces TLP.
// Layout identity as verified in rounds 4-6.
// ---------------------------------------------------------------------------
__global__ __launch_bounds__(256, 4) void hopfield(const half_t* __restrict__ q16,
                                                   const half_t* __restrict__ k16,
                                                   const half_t* __restrict__ v16,
                                                   const float* __restrict__ Wl2,
                                                   const float* __restrict__ c0acc,
                                                   float* __restrict__ y) {
    __shared__ __align__(16) half_t sm[SM_TOT];   // 26624 B
    const int t = threadIdx.x;
    const int lane = t & 63;
    const int w = t >> 6;
    const int lq = lane & 31;          // query col within chain tile
    const int hi = lane >> 5;          // lane half
    const int bh = blockIdx.x >> 1, seg = blockIdx.x & 1;
    const half_t* kg = k16 + (size_t)bh * (N_DIM * D_DIM);
    const half_t* vg = v16 + (size_t)bh * (N_DIM * D_DIM);
    const half_t* qg = q16 + (size_t)bh * (N_DIM * D_DIM) + seg * 256 * 8;
    const float* wl2p = Wl2 + (bh & 7) * (N_DIM * D_DIM) + seg * 256 * 8;

    {   // stage Kb rows + kt-blocked K^T / V^T (+ ones row 8)
        const int j0 = 2 * t;
        half8v r0 = *(const half8v*)(kg + j0 * 8);
        half8v r1 = *(const half8v*)(kg + j0 * 8 + 8);
        half8v v0 = *(const half8v*)(vg + j0 * 8);
        half8v v1 = *(const half8v*)(vg + j0 * 8 + 8);
        *(half8v*)&sm[SM_KB0 + j0 * 8]     = r0;
        *(half8v*)&sm[SM_KB0 + j0 * 8 + 8] = r1;
        const int kt = t >> 2, jp = j0 & 7;
        half_t* kb = &sm[SM_KT0 + kt * 72 + jp];
        half_t* vb = &sm[SM_VT0 + kt * 72 + jp];
        #pragma unroll
        for (int d = 0; d < 8; ++d) {
            half2v pk_; pk_[0] = r0[d]; pk_[1] = r1[d];
            *(half2v*)(kb + d * 8) = pk_;
            half2v pv_; pv_[0] = v0[d]; pv_[1] = v1[d];
            *(half2v*)(vb + d * 8) = pv_;
        }
        half2v one2; one2[0] = (half_t)1.f; one2[1] = (half_t)1.f;
        *(half2v*)(kb + 64) = one2;
        *(half2v*)(vb + 64) = one2;
    }
    __syncthreads();

    // S A-source: all lanes walk Kb row lq (hi lanes: same addr as lo sibling)
    const half_t* akb = sm + SM_KB0 + lq * 8;
    // U A-source: row d' (clamped to ones row for d'>8), kt-blocked
    int rowc = lq & 15; if (rowc > 8) rowc = 8;
    const half_t* aTk = sm + SM_KT0 + hi * 72 + rowc * 8;
    const half_t* aVk = sm + SM_VT0 + hi * 72 + rowc * 8;
    const f32x16 Zf16 = {};
    float fsum = 0.f;

    // initial Xi = (CQ*q), two chains; hi k-halves zeroed
    half8v bxA, bxB;
    {
        half8v qa = *(const half8v*)(qg + (w * 64 + lq) * 8);
        half8v qb = *(const half8v*)(qg + (w * 64 + 32 + lq) * 8);
        u32x4 wa = __builtin_bit_cast(u32x4, qa);
        u32x4 wb = __builtin_bit_cast(u32x4, qb);
        if (hi) {
            wa[0] = 0u; wa[1] = 0u; wa[2] = 0u; wa[3] = 0u;
            wb[0] = 0u; wb[1] = 0u; wb[2] = 0u; wb[3] = 0u;
        }
        bxA = __builtin_bit_cast(half8v, wa);
        bxB = __builtin_bit_cast(half8v, wb);
    }

    for (int it = 0; it < 4; ++it) {
        const half_t* aTit = (it == 3) ? aVk : aTk;
        f32x16 UA = {}, UB = {};
        #pragma unroll 4
        for (int tile = 0; tile < 16; ++tile) {
            half8v ak  = *(const half8v*)(akb + tile * 256);
            half8v aT0 = *(const half8v*)(aTit + tile * 288);
            half8v aT1 = *(const half8v*)(aTit + tile * 288 + 144);
            f32x16 SA = __builtin_amdgcn_mfma_f32_32x32x16_f16(ak, bxA, Zf16, 0, 0, 0);
            f32x16 SB = __builtin_amdgcn_mfma_f32_32x32x16_f16(ak, bxB, Zf16, 0, 0, 0);
            __builtin_amdgcn_s_setprio(1);
            // ---- chain A ----
            {
                unsigned wa = pku(__builtin_amdgcn_exp2f(SA[0]),  __builtin_amdgcn_exp2f(SA[1]));
                unsigned wb = pku(__builtin_amdgcn_exp2f(SA[2]),  __builtin_amdgcn_exp2f(SA[3]));
                unsigned wc = pku(__builtin_amdgcn_exp2f(SA[4]),  __builtin_amdgcn_exp2f(SA[5]));
                unsigned wd = pku(__builtin_amdgcn_exp2f(SA[6]),  __builtin_amdgcn_exp2f(SA[7]));
                unsigned we = pku(__builtin_amdgcn_exp2f(SA[8]),  __builtin_amdgcn_exp2f(SA[9]));
                unsigned wf = pku(__builtin_amdgcn_exp2f(SA[10]), __builtin_amdgcn_exp2f(SA[11]));
                unsigned wg = pku(__builtin_amdgcn_exp2f(SA[12]), __builtin_amdgcn_exp2f(SA[13]));
                unsigned wh = pku(__builtin_amdgcn_exp2f(SA[14]), __builtin_amdgcn_exp2f(SA[15]));
                plswap(wa, wc); plswap(wb, wd);
                plswap(we, wg); plswap(wf, wh);
                u32x4 c0 = {wa, wb, wc, wd};
                u32x4 c1 = {we, wf, wg, wh};
                UA = __builtin_amdgcn_mfma_f32_32x32x16_f16(aT0, __builtin_bit_cast(half8v, c0), UA, 0, 0, 0);
                UA = __builtin_amdgcn_mfma_f32_32x32x16_f16(aT1, __builtin_bit_cast(half8v, c1), UA, 0, 0, 0);
            }
            // ---- chain B ----
            {
                unsigned wa = pku(__builtin_amdgcn_exp2f(SB[0]),  __builtin_amdgcn_exp2f(SB[1]));
                unsigned wb = pku(__builtin_amdgcn_exp2f(SB[2]),  __builtin_amdgcn_exp2f(SB[3]));
                unsigned wc = pku(__builtin_amdgcn_exp2f(SB[4]),  __builtin_amdgcn_exp2f(SB[5]));
                unsigned wd = pku(__builtin_amdgcn_exp2f(SB[6]),  __builtin_amdgcn_exp2f(SB[7]));
                unsigned we = pku(__builtin_amdgcn_exp2f(SB[8]),  __builtin_amdgcn_exp2f(SB[9]));
                unsigned wf = pku(__builtin_amdgcn_exp2f(SB[10]), __builtin_amdgcn_exp2f(SB[11]));
                unsigned wg = pku(__builtin_amdgcn_exp2f(SB[12]), __builtin_amdgcn_exp2f(SB[13]));
                unsigned wh = pku(__builtin_amdgcn_exp2f(SB[14]), __builtin_amdgcn_exp2f(SB[15]));
                plswap(wa, wc); plswap(wb, wd);
                plswap(we, wg); plswap(wf, wh);
                u32x4 c0 = {wa, wb, wc, wd};
                u32x4 c1 = {we, wf, wg, wh};
                UB = __builtin_amdgcn_mfma_f32_32x32x16_f16(aT0, __builtin_bit_cast(half8v, c0), UB, 0, 0, 0);
                UB = __builtin_amdgcn_mfma_f32_32x32x16_f16(aT1, __builtin_bit_cast(half8v, c1), UB, 0, 0, 0);
            }
            __builtin_amdgcn_s_setprio(0);
        }
        float invA = __builtin_amdgcn_rcpf(bcast_lo(UA[4]));
        float invB = __builtin_amdgcn_rcpf(bcast_lo(UB[4]));
        if (it < 3) {
            float ciA = CQ * invA;
            unsigned A01 = pku(UA[0] * ciA, UA[1] * ciA);
            unsigned A23 = pku(UA[2] * ciA, UA[3] * ciA);
            unsigned za1 = 0u, za2 = 0u;
            plswap(A01, za1);
            plswap(A23, za2);
            u32x4 na = {A01, A23, za1, za2};
            bxA = __builtin_bit_cast(half8v, na);
            float ciB = CQ * invB;
            unsigned B01 = pku(UB[0] * ciB, UB[1] * ciB);
            unsigned B23 = pku(UB[2] * ciB, UB[3] * ciB);
            unsigned zb1 = 0u, zb2 = 0u;
            plswap(B01, zb1);
            plswap(B23, zb2);
            u32x4 nb = {B01, B23, zb1, zb2};
            bxB = __builtin_bit_cast(half8v, nb);
        } else {
            float4 wva = *(const float4*)&wl2p[(w * 64 + lq) * 8 + hi * 4];
            float4 wvb = *(const float4*)&wl2p[(w * 64 + 32 + lq) * 8 + hi * 4];
            fsum = invA * (UA[0] * wva.x + UA[1] * wva.y + UA[2] * wva.z + UA[3] * wva.w)
                 + invB * (UB[0] * wvb.x + UB[1] * wvb.y + UB[2] * wvb.z + UB[3] * wvb.w);
        }
    }
    float tot = block_reduce_256(fsum);
    if (t == 0) atomicAdd(&y[bh >> 3], tot);
    if (blockIdx.x == 0 && t < 32) {
        atomicAdd(&y[t], c0acc[0]);
    }
}

// ---------------------------------------------------------------------------
extern "C" void kernel_launch(void* const* d_in, const int* in_sizes, int n_in,
                              void* d_out, int out_size, void* d_ws, size_t ws_size,
                              hipStream_t stream) {
    const float* x   = (const float*)d_in[0];
    const float* g_q = (const float*)d_in[1];
    const float* b_q = (const float*)d_in[2];
    const float* g_k = (const float*)d_in[3];
    const float* b_k = (const float*)d_in[4];
    const float* g_v = (const float*)d_in[5];
    const float* b_v = (const float*)d_in[6];
    const float* Wq  = (const float*)d_in[7];
    const float* bq  = (const float*)d_in[8];
    const float* Wk  = (const float*)d_in[9];
    const float* bk  = (const float*)d_in[10];
    const float* Wv  = (const float*)d_in[11];
    const float* bv  = (const float*)d_in[12];
    const float* Wo  = (const float*)d_in[13];
    const float* bo  = (const float*)d_in[14];
    const float* Wl  = (const float*)d_in[15];
    const float* bl  = (const float*)d_in[16];
    float* out = (float*)d_out;

    float* ws = (float*)d_ws;
    float*  colsum = ws;                      // 192
    float*  b2     = ws + 192;                // 192
    float*  c0acc  = ws + 384;                // 1 (+pad to 64)
    float*  Wl2    = ws + 448;                // 32768
    half_t* WthF   = (half_t*)(ws + 33216);   // 98304 halves = 49152 floats
    half_t* qkv16  = (half_t*)(ws + 82368);   // 3*1048576 halves

    half_t* q16 = qkv16;
    half_t* k16 = qkv16 + 1048576;
    half_t* v16 = qkv16 + 2097152;

    prep_w    <<<192, 256, 0, stream>>>(Wq, Wk, Wv, g_q, g_k, g_v,
                                        b_q, b_k, b_v, bq, bk, bv, bl,
                                        WthF, colsum, b2, out, c0acc);
    ln_qkv_wl2<<<1056, 256, 0, stream>>>(x, WthF, b2, colsum, qkv16,
                                         Wl, Wo, bo, Wl2, c0acc);
    hopfield  <<<512, 256, 0, stream>>>(q16, k16, v16, Wl2, c0acc, out);
}

// Round 8
// 150.623 us; speedup vs baseline: 1.0601x; 1.0100x over previous
//
#include <hip/hip_runtime.h>

#define E_DIM 512
#define N_DIM 512
#define B_DIM 32
#define H_DIM 8
#define D_DIM 8
#define P3    192   // 3 * H * D

typedef _Float16 half_t;
typedef __attribute__((ext_vector_type(2))) _Float16 half2v;
typedef __attribute__((ext_vector_type(4))) _Float16 half4v;
typedef __attribute__((ext_vector_type(8))) _Float16 half8v;
typedef __attribute__((ext_vector_type(4))) float f32x4;
typedef __attribute__((ext_vector_type(16))) float f32x16;
typedef __attribute__((ext_vector_type(2))) unsigned int u32x2;
typedef __attribute__((ext_vector_type(4))) unsigned int u32x4;

#define XS_STRIDE 520   // ln x-tile stride (halves)
#define CQ 0.3606737602222409f   // 0.25 * log2(e)
#define LS_RS 136       // ln epilogue region stride (128 + 8 pad)

// hopfield LDS layout (half_t units):
//   KT16: [kt(64)][row(9)][key8] kt-blocked K^T, row 8 = ones. stride 72 halves.
//   VT16: same for V^T.
//   Kb:   [512][8] packed K rows (S-MFMA A-source).
#define SM_KT0 0
#define SM_VT0 4608
#define SM_KB0 9216
#define SM_TOT 13312

// ---------------------------------------------------------------------------
__device__ inline float block_reduce_256(float v) {
    __shared__ float red[4];
    #pragma unroll
    for (int m = 32; m >= 1; m >>= 1) v += __shfl_xor(v, m);
    int w = threadIdx.x >> 6;
    if ((threadIdx.x & 63) == 0) red[w] = v;
    __syncthreads();
    if (threadIdx.x == 0) v = red[0] + red[1] + red[2] + red[3];
    return v;
}

__device__ inline half8v cvt8(float4 a, float4 b) {
    half8v h;
    h[0] = (half_t)a.x; h[1] = (half_t)a.y; h[2] = (half_t)a.z; h[3] = (half_t)a.w;
    h[4] = (half_t)b.x; h[5] = (half_t)b.y; h[6] = (half_t)b.z; h[7] = (half_t)b.w;
    return h;
}

__device__ inline unsigned pku(float a, float b) {
    return __builtin_bit_cast(unsigned, __builtin_amdgcn_cvt_pkrtz(a, b));
}

// exchange: a' = [a.lo-lanes | b.lo-lanes], b' = [a.hi-lanes | b.hi-lanes]
__device__ inline void plswap(unsigned &a, unsigned &b) {
    u32x2 r = __builtin_amdgcn_permlane32_swap(a, b, false, false);
    a = r[0]; b = r[1];
}

// broadcast lo-half lanes' value to all 64 lanes (per 32-lane column)
__device__ inline float bcast_lo(float v) {
    unsigned u = __builtin_bit_cast(unsigned, v);
    u32x2 r = __builtin_amdgcn_permlane32_swap(u, u, false, false);
    return __builtin_bit_cast(float, r[0]);
}

// exp/pack/swap/U-MFMA block for one chain's 32x32 S tile (in registers)
#define PBLOCK(S, U, aT0, aT1) do {                                            \
    unsigned pa = pku(__builtin_amdgcn_exp2f((S)[0]),  __builtin_amdgcn_exp2f((S)[1]));  \
    unsigned pb = pku(__builtin_amdgcn_exp2f((S)[2]),  __builtin_amdgcn_exp2f((S)[3]));  \
    unsigned pc = pku(__builtin_amdgcn_exp2f((S)[4]),  __builtin_amdgcn_exp2f((S)[5]));  \
    unsigned pd = pku(__builtin_amdgcn_exp2f((S)[6]),  __builtin_amdgcn_exp2f((S)[7]));  \
    unsigned pe = pku(__builtin_amdgcn_exp2f((S)[8]),  __builtin_amdgcn_exp2f((S)[9]));  \
    unsigned pf = pku(__builtin_amdgcn_exp2f((S)[10]), __builtin_amdgcn_exp2f((S)[11])); \
    unsigned pg = pku(__builtin_amdgcn_exp2f((S)[12]), __builtin_amdgcn_exp2f((S)[13])); \
    unsigned ph = pku(__builtin_amdgcn_exp2f((S)[14]), __builtin_amdgcn_exp2f((S)[15])); \
    plswap(pa, pc); plswap(pb, pd);                                            \
    plswap(pe, pg); plswap(pf, ph);                                            \
    u32x4 q0 = {pa, pb, pc, pd};                                               \
    u32x4 q1 = {pe, pf, pg, ph};                                               \
    (U) = __builtin_amdgcn_mfma_f32_32x32x16_f16((aT0), __builtin_bit_cast(half8v, q0), (U), 0, 0, 0); \
    (U) = __builtin_amdgcn_mfma_f32_32x32x16_f16((aT1), __builtin_bit_cast(half8v, q1), (U), 0, 0, 0); \
} while (0)

// ---------------------------------------------------------------------------
// K0: prep. WthF = f16(W*g) in MFMA-fragment-coalesced layout.
// colsum[p'] = sum of f16-rounded w; b2[p'] = bias + W·ln_beta.
// Block 0 inits y[b]=bl, c0acc=0.
// ---------------------------------------------------------------------------
__global__ __launch_bounds__(256) void prep_w(const float* __restrict__ Wq,
                        const float* __restrict__ Wk, const float* __restrict__ Wv,
                        const float* __restrict__ gq, const float* __restrict__ gk,
                        const float* __restrict__ gv,
                        const float* __restrict__ bnq, const float* __restrict__ bnk,
                        const float* __restrict__ bnv,
                        const float* __restrict__ bq, const float* __restrict__ bk,
                        const float* __restrict__ bv,
                        const float* __restrict__ bl,
                        half_t* __restrict__ WthF, float* __restrict__ colsum,
                        float* __restrict__ b2, float* __restrict__ y,
                        float* __restrict__ c0acc) {
    int pp = blockIdx.x;     // 192
    int which = pp >> 6, p = pp & 63;
    int ct = pp >> 4, c16 = pp & 15;
    const float* W  = (which == 0) ? Wq  : (which == 1) ? Wk  : Wv;
    const float* g  = (which == 0) ? gq  : (which == 1) ? gk  : gv;
    const float* bn = (which == 0) ? bnq : (which == 1) ? bnk : bnv;
    const float* bb = (which == 0) ? bq  : (which == 1) ? bk  : bv;
    int t = threadIdx.x;
    if (pp == 0) {
        if (t < 32) y[t] = bl[0];
        if (t == 32) c0acc[0] = 0.f;
    }
    float cs = 0.f, dt = 0.f;
    #pragma unroll
    for (int l = 0; l < 2; ++l) {
        int e = t + l * 256;
        float wv = W[p * E_DIM + e];
        half_t wh = (half_t)(wv * g[e]);
        int k32 = e >> 5, g2 = (e >> 3) & 3, j = e & 7;
        WthF[(((size_t)(ct * 16 + k32) * 64) + g2 * 16 + c16) * 8 + j] = wh;
        cs += (float)wh;
        dt += wv * bn[e];
    }
    cs = block_reduce_256(cs);
    __syncthreads();
    dt = block_reduce_256(dt);
    if (t == 0) { colsum[pp] = cs; b2[pp] = dt + bb[p]; }
}

// ---------------------------------------------------------------------------
// K1: blocks 0-1023: fused LN+QKV with LDS-staged x (coalesced loads) and
// coalesced WthF B-fragments. k32=0 B-frags prefetched pre-barrier so the
// K-loop entry doesn't eat a cold L2 latency. Epilogue transposes through
// LDS -> coalesced 8B stores. Blocks 1024-1055: Wl2 via MFMA.
// q output is pre-scaled by CQ (hopfield consumes Xi = CQ * q).
// ---------------------------------------------------------------------------
__global__ __launch_bounds__(256) void ln_qkv_wl2(const float* __restrict__ x,
                                              const half_t* __restrict__ WthF,
                                              const float* __restrict__ b2,
                                              const float* __restrict__ colsum,
                                              half_t* __restrict__ qkv16,
                                              const float* __restrict__ Wl,
                                              const float* __restrict__ Wo,
                                              const float* __restrict__ bo,
                                              float* __restrict__ Wl2,
                                              float* __restrict__ c0acc) {
    __shared__ half_t Xs[16 * XS_STRIDE];   // 16.25 KB
    __shared__ half_t Ls[24 * LS_RS];       // 6.4 KB epilogue transpose
    __shared__ float stats[16][2];
    if (blockIdx.x < 1024) {
        const int t = threadIdx.x;
        const int lane = t & 63;
        const int w = t >> 6;
        const int g2 = lane >> 4, c16 = lane & 15;
        const int row0 = blockIdx.x * 16;
        const half_t* wf = WthF + (size_t)w * 3 * 16 * 512;
        // ---- prefetch k32=0 B-frags (L2) to overlap with x HBM latency ----
        half8v pb0 = *(const half8v*)(wf + (size_t)( 0) * 512 + lane * 8);
        half8v pb1 = *(const half8v*)(wf + (size_t)(16) * 512 + lane * 8);
        half8v pb2 = *(const half8v*)(wf + (size_t)(32) * 512 + lane * 8);
        // ---- stage x -> f16 LDS (coalesced: 16-lane groups read 256B runs) ----
        {
            const int row = t >> 4, c = t & 15;
            const float4* xrow = (const float4*)(x + (size_t)(row0 + row) * E_DIM);
            float sx = 0.f, sxx = 0.f;
            #pragma unroll
            for (int l = 0; l < 8; ++l) {
                int f4 = c + l * 16;
                float4 a = xrow[f4];
                sx  += a.x + a.y + a.z + a.w;
                sxx += a.x*a.x + a.y*a.y + a.z*a.z + a.w*a.w;
                half4v h;
                h[0] = (half_t)a.x; h[1] = (half_t)a.y;
                h[2] = (half_t)a.z; h[3] = (half_t)a.w;
                *(half4v*)&Xs[row * XS_STRIDE + f4 * 4] = h;
            }
            #pragma unroll
            for (int m = 1; m <= 8; m <<= 1) {
                sx += __shfl_xor(sx, m); sxx += __shfl_xor(sxx, m);
            }
            if (c == 0) {
                float mean = sx * (1.f / E_DIM);
                float var  = sxx * (1.f / E_DIM) - mean * mean;
                stats[row][0] = mean;
                stats[row][1] = rsqrtf(var + 1e-5f);
            }
        }
        __syncthreads();
        // ---- K-loop: A from LDS, B from WthF (k32=0 from prefetch regs) ----
        f32x4 acc[3] = {{0.f,0.f,0.f,0.f},{0.f,0.f,0.f,0.f},{0.f,0.f,0.f,0.f}};
        {
            half8v af = *(const half8v*)&Xs[c16 * XS_STRIDE + g2 * 8];
            acc[0] = __builtin_amdgcn_mfma_f32_16x16x32_f16(af, pb0, acc[0], 0, 0, 0);
            acc[1] = __builtin_amdgcn_mfma_f32_16x16x32_f16(af, pb1, acc[1], 0, 0, 0);
            acc[2] = __builtin_amdgcn_mfma_f32_16x16x32_f16(af, pb2, acc[2], 0, 0, 0);
        }
        #pragma unroll 5
        for (int k32 = 1; k32 < 16; ++k32) {
            half8v af = *(const half8v*)&Xs[c16 * XS_STRIDE + k32 * 32 + g2 * 8];
            #pragma unroll
            for (int nt = 0; nt < 3; ++nt) {
                half8v bf = *(const half8v*)(wf + ((size_t)(nt * 16 + k32)) * 512 + lane * 8);
                acc[nt] = __builtin_amdgcn_mfma_f32_16x16x32_f16(af, bf, acc[nt], 0, 0, 0);
            }
        }
        // ---- epilogue: LN correction + q-prescale -> LDS transpose ----
        #pragma unroll
        for (int nt = 0; nt < 3; ++nt) {
            int pp = w * 48 + nt * 16 + c16;
            float cs = colsum[pp], bb = b2[pp];
            float qsc = (pp < 64) ? CQ : 1.0f;
            int region = pp >> 3, d = pp & 7;
            #pragma unroll
            for (int r = 0; r < 4; ++r) {
                int rowi = g2 * 4 + r;
                float val = (stats[rowi][1] * (acc[nt][r] - stats[rowi][0] * cs) + bb) * qsc;
                Ls[region * LS_RS + rowi * 8 + d] = (half_t)val;
            }
        }
        __syncthreads();
        // ---- coalesced stores: 768 chunks of 8B, 3 per thread ----
        const int b = row0 >> 9, n0 = row0 & 511;
        #pragma unroll
        for (int l = 0; l < 3; ++l) {
            int c = t + l * 256;
            int region = c >> 5, off = (c & 31) * 4;   // off = rowi*8 + d0
            int which = region >> 3, h = region & 7;
            half4v v = *(const half4v*)&Ls[region * LS_RS + off];
            half_t* dst0 = qkv16 + (size_t)which * (B_DIM * H_DIM * N_DIM * D_DIM);
            int rowi = off >> 3, d0 = off & 7;
            *(half4v*)&dst0[(((size_t)(b * H_DIM + h)) * N_DIM + n0 + rowi) * D_DIM + d0] = v;
        }
    } else {
        // ---- Wl2 MFMA: blk in [0,32) ----
        const int blk = blockIdx.x - 1024;
        const int t = threadIdx.x;
        const int lane = t & 63;
        const int w = t >> 6;
        const int g2 = lane >> 4, c16 = lane & 15;
        const int n0 = blk * 16;
        const int pcol = w * 16;
        f32x4 acc = {0.f, 0.f, 0.f, 0.f};
        float pc = 0.f;
        const float* arow = Wl + (size_t)(n0 + c16) * E_DIM;
        #pragma unroll 2
        for (int k0 = 0; k0 < E_DIM; k0 += 32) {
            int kbase = k0 + g2 * 8;
            float4 a0 = *(const float4*)(arow + kbase);
            float4 a1 = *(const float4*)(arow + kbase + 4);
            if (w == 0) {
                float4 b0 = *(const float4*)(bo + kbase);
                float4 b1 = *(const float4*)(bo + kbase + 4);
                pc += a0.x*b0.x + a0.y*b0.y + a0.z*b0.z + a0.w*b0.w
                    + a1.x*b1.x + a1.y*b1.y + a1.z*b1.z + a1.w*b1.w;
            }
            half8v af = cvt8(a0, a1);
            half8v bf;
            #pragma unroll
            for (int j = 0; j < 8; ++j)
                bf[j] = (half_t)Wo[(size_t)(kbase + j) * 64 + pcol + c16];
            acc = __builtin_amdgcn_mfma_f32_16x16x32_f16(af, bf, acc, 0, 0, 0);
        }
        int p = pcol + c16, h = p >> 3, d = p & 7;
        #pragma unroll
        for (int r = 0; r < 4; ++r) {
            int n = n0 + g2 * 4 + r;
            Wl2[h * (N_DIM * D_DIM) + n * D_DIM + d] = acc[r];
        }
        if (w == 0) {
            pc += __shfl_xor(pc, 16); pc += __shfl_xor(pc, 32);
            pc += __shfl_xor(pc, 1);  pc += __shfl_xor(pc, 2);
            pc += __shfl_xor(pc, 4);  pc += __shfl_xor(pc, 8);
            if (lane == 0) atomicAdd(c0acc, pc);
        }
    }
}

// ---------------------------------------------------------------------------
// K2: 32x32 chained-MFMA Hopfield, two chains/wave, EXPLICIT 2-stage pipeline.
// Steady state: tile t+1's {3 ds_reads + 2 S-MFMAs} issue BEFORE tile t's
// ~600-cycle exp/pack/U block — the trans burst hides all load/MFMA latency.
// __launch_bounds__(256,2): grid 512 gives 2 blocks/CU anyway; the 256-VGPR
// budget (vs 128 at min-waves=4) gives the allocator room for the pipeline's
// live state (~150 regs) without spills — R7's 128-cap left no slack, which
// is the suspected stall source. setprio kept (independent-wave regime).
// ---------------------------------------------------------------------------
__global__ __launch_bounds__(256, 2) void hopfield(const half_t* __restrict__ q16,
                                                   const half_t* __restrict__ k16,
                                                   const half_t* __restrict__ v16,
                                                   const float* __restrict__ Wl2,
                                                   const float* __restrict__ c0acc,
                                                   float* __restrict__ y) {
    __shared__ __align__(16) half_t sm[SM_TOT];   // 26624 B
    const int t = threadIdx.x;
    const int lane = t & 63;
    const int w = t >> 6;
    const int lq = lane & 31;          // query col within chain tile
    const int hi = lane >> 5;          // lane half
    const int bh = blockIdx.x >> 1, seg = blockIdx.x & 1;
    const half_t* kg = k16 + (size_t)bh * (N_DIM * D_DIM);
    const half_t* vg = v16 + (size_t)bh * (N_DIM * D_DIM);
    const half_t* qg = q16 + (size_t)bh * (N_DIM * D_DIM) + seg * 256 * 8;
    const float* wl2p = Wl2 + (bh & 7) * (N_DIM * D_DIM) + seg * 256 * 8;

    {   // stage Kb rows + kt-blocked K^T / V^T (+ ones row 8)
        const int j0 = 2 * t;
        half8v r0 = *(const half8v*)(kg + j0 * 8);
        half8v r1 = *(const half8v*)(kg + j0 * 8 + 8);
        half8v v0 = *(const half8v*)(vg + j0 * 8);
        half8v v1 = *(const half8v*)(vg + j0 * 8 + 8);
        *(half8v*)&sm[SM_KB0 + j0 * 8]     = r0;
        *(half8v*)&sm[SM_KB0 + j0 * 8 + 8] = r1;
        const int kt = t >> 2, jp = j0 & 7;
        half_t* kb = &sm[SM_KT0 + kt * 72 + jp];
        half_t* vb = &sm[SM_VT0 + kt * 72 + jp];
        #pragma unroll
        for (int d = 0; d < 8; ++d) {
            half2v pk_; pk_[0] = r0[d]; pk_[1] = r1[d];
            *(half2v*)(kb + d * 8) = pk_;
            half2v pv_; pv_[0] = v0[d]; pv_[1] = v1[d];
            *(half2v*)(vb + d * 8) = pv_;
        }
        half2v one2; one2[0] = (half_t)1.f; one2[1] = (half_t)1.f;
        *(half2v*)(kb + 64) = one2;
        *(half2v*)(vb + 64) = one2;
    }
    __syncthreads();

    // S A-source: all lanes walk Kb row lq (hi lanes: same addr as lo sibling)
    const half_t* akb = sm + SM_KB0 + lq * 8;
    // U A-source: row d' (clamped to ones row for d'>8), kt-blocked
    int rowc = lq & 15; if (rowc > 8) rowc = 8;
    const half_t* aTk = sm + SM_KT0 + hi * 72 + rowc * 8;
    const half_t* aVk = sm + SM_VT0 + hi * 72 + rowc * 8;
    const f32x16 Zf16 = {};
    float fsum = 0.f;

    // initial Xi = (CQ*q), two chains; hi k-halves zeroed
    half8v bxA, bxB;
    {
        half8v qa = *(const half8v*)(qg + (w * 64 + lq) * 8);
        half8v qb = *(const half8v*)(qg + (w * 64 + 32 + lq) * 8);
        u32x4 wa = __builtin_bit_cast(u32x4, qa);
        u32x4 wb = __builtin_bit_cast(u32x4, qb);
        if (hi) {
            wa[0] = 0u; wa[1] = 0u; wa[2] = 0u; wa[3] = 0u;
            wb[0] = 0u; wb[1] = 0u; wb[2] = 0u; wb[3] = 0u;
        }
        bxA = __builtin_bit_cast(half8v, wa);
        bxB = __builtin_bit_cast(half8v, wb);
    }

    for (int it = 0; it < 4; ++it) {
        const half_t* aTit = (it == 3) ? aVk : aTk;
        f32x16 UA = {}, UB = {};
        // ---- prologue: tile 0 loads + S-MFMAs ----
        half8v ak  = *(const half8v*)akb;
        half8v aT0 = *(const half8v*)aTit;
        half8v aT1 = *(const half8v*)(aTit + 144);
        f32x16 SA = __builtin_amdgcn_mfma_f32_32x32x16_f16(ak, bxA, Zf16, 0, 0, 0);
        f32x16 SB = __builtin_amdgcn_mfma_f32_32x32x16_f16(ak, bxB, Zf16, 0, 0, 0);
        // ---- steady state: issue t+1 loads + S before t's exp/U block ----
        #pragma unroll 5
        for (int tile = 0; tile < 15; ++tile) {
            half8v akn  = *(const half8v*)(akb + (tile + 1) * 256);
            half8v aT0n = *(const half8v*)(aTit + (tile + 1) * 288);
            half8v aT1n = *(const half8v*)(aTit + (tile + 1) * 288 + 144);
            f32x16 SAn = __builtin_amdgcn_mfma_f32_32x32x16_f16(akn, bxA, Zf16, 0, 0, 0);
            f32x16 SBn = __builtin_amdgcn_mfma_f32_32x32x16_f16(akn, bxB, Zf16, 0, 0, 0);
            __builtin_amdgcn_s_setprio(1);
            PBLOCK(SA, UA, aT0, aT1);
            PBLOCK(SB, UB, aT0, aT1);
            __builtin_amdgcn_s_setprio(0);
            SA = SAn; SB = SBn; aT0 = aT0n; aT1 = aT1n;
        }
        // ---- epilogue: tile 15 ----
        __builtin_amdgcn_s_setprio(1);
        PBLOCK(SA, UA, aT0, aT1);
        PBLOCK(SB, UB, aT0, aT1);
        __builtin_amdgcn_s_setprio(0);

        float invA = __builtin_amdgcn_rcpf(bcast_lo(UA[4]));
        float invB = __builtin_amdgcn_rcpf(bcast_lo(UB[4]));
        if (it < 3) {
            float ciA = CQ * invA;
            unsigned A01 = pku(UA[0] * ciA, UA[1] * ciA);
            unsigned A23 = pku(UA[2] * ciA, UA[3] * ciA);
            unsigned za1 = 0u, za2 = 0u;
            plswap(A01, za1);
            plswap(A23, za2);
            u32x4 na = {A01, A23, za1, za2};
            bxA = __builtin_bit_cast(half8v, na);
            float ciB = CQ * invB;
            unsigned B01 = pku(UB[0] * ciB, UB[1] * ciB);
            unsigned B23 = pku(UB[2] * ciB, UB[3] * ciB);
            unsigned zb1 = 0u, zb2 = 0u;
            plswap(B01, zb1);
            plswap(B23, zb2);
            u32x4 nb = {B01, B23, zb1, zb2};
            bxB = __builtin_bit_cast(half8v, nb);
        } else {
            float4 wva = *(const float4*)&wl2p[(w * 64 + lq) * 8 + hi * 4];
            float4 wvb = *(const float4*)&wl2p[(w * 64 + 32 + lq) * 8 + hi * 4];
            fsum = invA * (UA[0] * wva.x + UA[1] * wva.y + UA[2] * wva.z + UA[3] * wva.w)
                 + invB * (UB[0] * wvb.x + UB[1] * wvb.y + UB[2] * wvb.z + UB[3] * wvb.w);
        }
    }
    float tot = block_reduce_256(fsum);
    if (t == 0) atomicAdd(&y[bh >> 3], tot);
    if (blockIdx.x == 0 && t < 32) {
        atomicAdd(&y[t], c0acc[0]);
    }
}

// ---------------------------------------------------------------------------
extern "C" void kernel_launch(void* const* d_in, const int* in_sizes, int n_in,
                              void* d_out, int out_size, void* d_ws, size_t ws_size,
                              hipStream_t stream) {
    const float* x   = (const float*)d_in[0];
    const float* g_q = (const float*)d_in[1];
    const float* b_q = (const float*)d_in[2];
    const float* g_k = (const float*)d_in[3];
    const float* b_k = (const float*)d_in[4];
    const float* g_v = (const float*)d_in[5];
    const float* b_v = (const float*)d_in[6];
    const float* Wq  = (const float*)d_in[7];
    const float* bq  = (const float*)d_in[8];
    const float* Wk  = (const float*)d_in[9];
    const float* bk  = (const float*)d_in[10];
    const float* Wv  = (const float*)d_in[11];
    const float* bv  = (const float*)d_in[12];
    const float* Wo  = (const float*)d_in[13];
    const float* bo  = (const float*)d_in[14];
    const float* Wl  = (const float*)d_in[15];
    const float* bl  = (const float*)d_in[16];
    float* out = (float*)d_out;

    float* ws = (float*)d_ws;
    float*  colsum = ws;                      // 192
    float*  b2     = ws + 192;                // 192
    float*  c0acc  = ws + 384;                // 1 (+pad to 64)
    float*  Wl2    = ws + 448;                // 32768
    half_t* WthF   = (half_t*)(ws + 33216);   // 98304 halves = 49152 floats
    half_t* qkv16  = (half_t*)(ws + 82368);   // 3*1048576 halves

    half_t* q16 = qkv16;
    half_t* k16 = qkv16 + 1048576;
    half_t* v16 = qkv16 + 2097152;

    prep_w    <<<192, 256, 0, stream>>>(Wq, Wk, Wv, g_q, g_k, g_v,
                                        b_q, b_k, b_v, bq, bk, bv, bl,
                                        WthF, colsum, b2, out, c0acc);
    ln_qkv_wl2<<<1056, 256, 0, stream>>>(x, WthF, b2, colsum, qkv16,
                                         Wl, Wo, bo, Wl2, c0acc);
    hopfield  <<<512, 256, 0, stream>>>(q16, k16, v16, Wl2, c0acc, out);
}